// Round 1
// baseline (2943.656 us; speedup 1.0000x reference)
//
#include <hip/hip_runtime.h>

#define LRELU(v) ((v) >= 0.0f ? (v) : 0.01f * (v))

// ---------------------------------------------------------------------------
// Scatter phase: agg[dst] += x[src]  (raw features, F = 5 or 12)
// ---------------------------------------------------------------------------
template<int F>
__global__ __launch_bounds__(256)
void scatter_add_k(const float* __restrict__ x, const int* __restrict__ src,
                   const int* __restrict__ dst, int E, float* __restrict__ agg)
{
    int stride = gridDim.x * blockDim.x;
    for (int e = blockIdx.x * blockDim.x + threadIdx.x; e < E; e += stride) {
        int s = src[e];
        int d = dst[e];
        const float* xs = x + (size_t)s * F;
        float* ag = agg + (size_t)d * F;
        #pragma unroll
        for (int f = 0; f < F; ++f)
            atomicAdd(ag + f, xs[f]);
    }
}

// Destinations are the 8 device rows: stage in LDS, one global flush per block.
template<int F>
__global__ __launch_bounds__(256)
void scatter_dev_k(const float* __restrict__ x, const int* __restrict__ src,
                   const int* __restrict__ dst, int E, float* __restrict__ agg)
{
    __shared__ float s_agg[8 * F];
    for (int i = threadIdx.x; i < 8 * F; i += 256) s_agg[i] = 0.0f;
    __syncthreads();
    int stride = gridDim.x * blockDim.x;
    for (int e = blockIdx.x * blockDim.x + threadIdx.x; e < E; e += stride) {
        int s = src[e];
        int d = dst[e];
        const float* xs = x + (size_t)s * F;
        #pragma unroll
        for (int f = 0; f < F; ++f)
            atomicAdd(&s_agg[d * F + f], xs[f]);
    }
    __syncthreads();
    for (int i = threadIdx.x; i < 8 * F; i += 256)
        atomicAdd(&agg[i], s_agg[i]);
}

// ---------------------------------------------------------------------------
// Finalize tasks: f[53] = [aggD(5), aggDev(12), aggTo(12), aggFrom(12), x(12)]
// out = lrelu(LN(f @ sW(53x16) + b))
// ---------------------------------------------------------------------------
__global__ __launch_bounds__(256)
void finalize_tasks_k(const float* __restrict__ aggD, const float* __restrict__ aggDev,
                      const float* __restrict__ aggTo, const float* __restrict__ aggFrom,
                      const float* __restrict__ x,
                      const float* __restrict__ W_rel5, const float* __restrict__ W_rel12,
                      const float* __restrict__ b_rel, const float* __restrict__ W_root12,
                      const float* __restrict__ ln_g, const float* __restrict__ ln_b,
                      float* __restrict__ out, int N)
{
    __shared__ __align__(16) float sW[53 * 16];
    __shared__ float sb[16], sg[16], sbt[16];
    const int t = threadIdx.x;
    for (int i = t; i < 80; i += 256) sW[i] = W_rel5[i];               // W_rel5[0]
    for (int i = t; i < 192; i += 256) {
        sW[80  + i] = W_rel12[384 + i];                                // W_rel12[2]
        sW[272 + i] = W_rel12[768 + i];                                // W_rel12[4]
        sW[464 + i] = W_rel12[960 + i];                                // W_rel12[5]
        sW[656 + i] = W_root12[i] + W_root12[384 + i]
                    + W_root12[768 + i] + W_root12[960 + i];           // summed roots
    }
    if (t < 16) {
        sb[t]  = b_rel[t] + b_rel[48 + t] + b_rel[96 + t] + b_rel[112 + t];
        sg[t]  = ln_g[t];
        sbt[t] = ln_b[t];
    }
    __syncthreads();
    const int i = blockIdx.x * 256 + t;
    if (i >= N) return;

    float f[53];
    {
        const float* p = aggD + (size_t)i * 5;
        #pragma unroll
        for (int j = 0; j < 5; ++j) f[j] = p[j];
        p = aggDev + (size_t)i * 12;
        #pragma unroll
        for (int j = 0; j < 12; ++j) f[5 + j] = p[j];
        p = aggTo + (size_t)i * 12;
        #pragma unroll
        for (int j = 0; j < 12; ++j) f[17 + j] = p[j];
        p = aggFrom + (size_t)i * 12;
        #pragma unroll
        for (int j = 0; j < 12; ++j) f[29 + j] = p[j];
        p = x + (size_t)i * 12;
        #pragma unroll
        for (int j = 0; j < 12; ++j) f[41 + j] = p[j];
    }

    float acc[16];
    #pragma unroll
    for (int k = 0; k < 16; ++k) acc[k] = sb[k];
    const float4* w4 = (const float4*)sW;
    #pragma unroll
    for (int j = 0; j < 53; ++j) {
        const float fj = f[j];
        float4 w0 = w4[j * 4 + 0], w1 = w4[j * 4 + 1];
        float4 w2 = w4[j * 4 + 2], w3 = w4[j * 4 + 3];
        acc[0]  = fmaf(fj, w0.x, acc[0]);  acc[1]  = fmaf(fj, w0.y, acc[1]);
        acc[2]  = fmaf(fj, w0.z, acc[2]);  acc[3]  = fmaf(fj, w0.w, acc[3]);
        acc[4]  = fmaf(fj, w1.x, acc[4]);  acc[5]  = fmaf(fj, w1.y, acc[5]);
        acc[6]  = fmaf(fj, w1.z, acc[6]);  acc[7]  = fmaf(fj, w1.w, acc[7]);
        acc[8]  = fmaf(fj, w2.x, acc[8]);  acc[9]  = fmaf(fj, w2.y, acc[9]);
        acc[10] = fmaf(fj, w2.z, acc[10]); acc[11] = fmaf(fj, w2.w, acc[11]);
        acc[12] = fmaf(fj, w3.x, acc[12]); acc[13] = fmaf(fj, w3.y, acc[13]);
        acc[14] = fmaf(fj, w3.z, acc[14]); acc[15] = fmaf(fj, w3.w, acc[15]);
    }

    float mu = 0.0f;
    #pragma unroll
    for (int k = 0; k < 16; ++k) mu += acc[k];
    mu *= (1.0f / 16.0f);
    float var = 0.0f;
    #pragma unroll
    for (int k = 0; k < 16; ++k) { float d = acc[k] - mu; var = fmaf(d, d, var); }
    var *= (1.0f / 16.0f);
    const float r = rsqrtf(var + 1e-5f);
    float* op = out + (size_t)i * 16;
    #pragma unroll
    for (int k = 0; k < 16; ++k) {
        float v = (acc[k] - mu) * r * sg[k] + sbt[k];
        op[k] = LRELU(v);
    }
}

// ---------------------------------------------------------------------------
// Finalize data: f[29] = [aggT(12), aggDev(12), x(5)]
// ---------------------------------------------------------------------------
__global__ __launch_bounds__(256)
void finalize_data_k(const float* __restrict__ aggT, const float* __restrict__ aggDev,
                     const float* __restrict__ x,
                     const float* __restrict__ W_rel12, const float* __restrict__ W_root5,
                     const float* __restrict__ b_rel,
                     const float* __restrict__ ln_g, const float* __restrict__ ln_b,
                     float* __restrict__ out, int N)
{
    __shared__ __align__(16) float sW[29 * 16];
    __shared__ float sb[16], sg[16], sbt[16];
    const int t = threadIdx.x;
    for (int i = t; i < 192; i += 256) {
        sW[i]       = W_rel12[i];          // W_rel12[0] tasks->data
        sW[192 + i] = W_rel12[576 + i];    // W_rel12[3] devices->data
    }
    for (int i = t; i < 80; i += 256)
        sW[384 + i] = W_root5[i] + W_root5[80 + i];  // W_root5[0]+W_root5[1]
    if (t < 16) {
        sb[t]  = b_rel[16 + t] + b_rel[80 + t];
        sg[t]  = ln_g[16 + t];
        sbt[t] = ln_b[16 + t];
    }
    __syncthreads();
    const int i = blockIdx.x * 256 + t;
    if (i >= N) return;

    float f[29];
    {
        const float* p = aggT + (size_t)i * 12;
        #pragma unroll
        for (int j = 0; j < 12; ++j) f[j] = p[j];
        p = aggDev + (size_t)i * 12;
        #pragma unroll
        for (int j = 0; j < 12; ++j) f[12 + j] = p[j];
        p = x + (size_t)i * 5;
        #pragma unroll
        for (int j = 0; j < 5; ++j) f[24 + j] = p[j];
    }

    float acc[16];
    #pragma unroll
    for (int k = 0; k < 16; ++k) acc[k] = sb[k];
    const float4* w4 = (const float4*)sW;
    #pragma unroll
    for (int j = 0; j < 29; ++j) {
        const float fj = f[j];
        float4 w0 = w4[j * 4 + 0], w1 = w4[j * 4 + 1];
        float4 w2 = w4[j * 4 + 2], w3 = w4[j * 4 + 3];
        acc[0]  = fmaf(fj, w0.x, acc[0]);  acc[1]  = fmaf(fj, w0.y, acc[1]);
        acc[2]  = fmaf(fj, w0.z, acc[2]);  acc[3]  = fmaf(fj, w0.w, acc[3]);
        acc[4]  = fmaf(fj, w1.x, acc[4]);  acc[5]  = fmaf(fj, w1.y, acc[5]);
        acc[6]  = fmaf(fj, w1.z, acc[6]);  acc[7]  = fmaf(fj, w1.w, acc[7]);
        acc[8]  = fmaf(fj, w2.x, acc[8]);  acc[9]  = fmaf(fj, w2.y, acc[9]);
        acc[10] = fmaf(fj, w2.z, acc[10]); acc[11] = fmaf(fj, w2.w, acc[11]);
        acc[12] = fmaf(fj, w3.x, acc[12]); acc[13] = fmaf(fj, w3.y, acc[13]);
        acc[14] = fmaf(fj, w3.z, acc[14]); acc[15] = fmaf(fj, w3.w, acc[15]);
    }

    float mu = 0.0f;
    #pragma unroll
    for (int k = 0; k < 16; ++k) mu += acc[k];
    mu *= (1.0f / 16.0f);
    float var = 0.0f;
    #pragma unroll
    for (int k = 0; k < 16; ++k) { float d = acc[k] - mu; var = fmaf(d, d, var); }
    var *= (1.0f / 16.0f);
    const float r = rsqrtf(var + 1e-5f);
    float* op = out + (size_t)i * 16;
    #pragma unroll
    for (int k = 0; k < 16; ++k) {
        float v = (acc[k] - mu) * r * sg[k] + sbt[k];
        op[k] = LRELU(v);
    }
}

// ---------------------------------------------------------------------------
// Finalize devices (8 rows, trivial)
// ---------------------------------------------------------------------------
__global__ void finalize_dev_k(const float* __restrict__ aggT, const float* __restrict__ aggD,
                               const float* __restrict__ x,
                               const float* __restrict__ W_rel12, const float* __restrict__ W_rel5,
                               const float* __restrict__ b_rel, const float* __restrict__ W_root12,
                               const float* __restrict__ ln_g, const float* __restrict__ ln_b,
                               float* __restrict__ out, int N)
{
    int i = threadIdx.x;
    if (i >= N) return;
    float acc[16];
    #pragma unroll
    for (int k = 0; k < 16; ++k) acc[k] = b_rel[32 + k] + b_rel[64 + k];
    #pragma unroll
    for (int j = 0; j < 12; ++j) {                       // aggT @ W_rel12[1]
        float fj = aggT[i * 12 + j];
        #pragma unroll
        for (int k = 0; k < 16; ++k) acc[k] = fmaf(fj, W_rel12[192 + j * 16 + k], acc[k]);
    }
    #pragma unroll
    for (int j = 0; j < 5; ++j) {                        // aggD @ W_rel5[1]
        float fj = aggD[i * 5 + j];
        #pragma unroll
        for (int k = 0; k < 16; ++k) acc[k] = fmaf(fj, W_rel5[80 + j * 16 + k], acc[k]);
    }
    #pragma unroll
    for (int j = 0; j < 12; ++j) {                       // x @ (W_root12[1]+W_root12[3])
        float fj = x[i * 12 + j];
        #pragma unroll
        for (int k = 0; k < 16; ++k)
            acc[k] = fmaf(fj, W_root12[192 + j * 16 + k] + W_root12[576 + j * 16 + k], acc[k]);
    }
    float mu = 0.0f;
    #pragma unroll
    for (int k = 0; k < 16; ++k) mu += acc[k];
    mu *= (1.0f / 16.0f);
    float var = 0.0f;
    #pragma unroll
    for (int k = 0; k < 16; ++k) { float d = acc[k] - mu; var = fmaf(d, d, var); }
    var *= (1.0f / 16.0f);
    const float r = rsqrtf(var + 1e-5f);
    #pragma unroll
    for (int k = 0; k < 16; ++k) {
        float v = (acc[k] - mu) * r * ln_g[32 + k] + ln_b[32 + k];
        out[i * 16 + k] = LRELU(v);
    }
}

// ---------------------------------------------------------------------------
extern "C" void kernel_launch(void* const* d_in, const int* in_sizes, int n_in,
                              void* d_out, int out_size, void* d_ws, size_t ws_size,
                              hipStream_t stream)
{
    const float* x_tasks = (const float*)d_in[0];
    const float* x_data  = (const float*)d_in[1];
    const float* x_dev   = (const float*)d_in[2];
    const int* ei_dt    = (const int*)d_in[3];   // data -> tasks
    const int* ei_td    = (const int*)d_in[4];   // tasks -> data
    const int* ei_tdev  = (const int*)d_in[5];   // tasks -> devices
    const int* ei_devt  = (const int*)d_in[6];   // devices -> tasks
    const int* ei_ddev  = (const int*)d_in[7];   // data -> devices
    const int* ei_devd  = (const int*)d_in[8];   // devices -> data
    const int* ei_to    = (const int*)d_in[9];   // tt_to
    const int* ei_from  = (const int*)d_in[10];  // tt_from
    const float* W_rel5   = (const float*)d_in[11];
    const float* W_rel12  = (const float*)d_in[12];
    const float* b_rel    = (const float*)d_in[13];
    const float* W_root5  = (const float*)d_in[14];
    const float* W_root12 = (const float*)d_in[15];
    const float* ln_g     = (const float*)d_in[16];
    const float* ln_b     = (const float*)d_in[17];

    const int NT   = in_sizes[0] / 12;
    const int ND   = in_sizes[1] / 5;
    const int NDEV = in_sizes[2] / 12;
    const int E_dt   = in_sizes[3]  / 2;
    const int E_td   = in_sizes[4]  / 2;
    const int E_tdev = in_sizes[5]  / 2;
    const int E_devt = in_sizes[6]  / 2;
    const int E_ddev = in_sizes[7]  / 2;
    const int E_devd = in_sizes[8]  / 2;
    const int E_to   = in_sizes[9]  / 2;
    const int E_from = in_sizes[10] / 2;

    float* ws = (float*)d_ws;
    size_t o = 0;
    float* aggD_t   = ws + o; o += (size_t)NT * 5;
    float* aggDev_t = ws + o; o += (size_t)NT * 12;
    float* aggTo    = ws + o; o += (size_t)NT * 12;
    float* aggFrom  = ws + o; o += (size_t)NT * 12;
    float* aggT_d   = ws + o; o += (size_t)ND * 12;
    float* aggDev_d = ws + o; o += (size_t)ND * 12;
    float* aggT_dev = ws + o; o += 96;
    float* aggD_dev = ws + o; o += 40;

    hipMemsetAsync(d_ws, 0, o * sizeof(float), stream);

    auto nb = [](int e) { return (e + 255) / 256; };

    scatter_add_k<5> <<<nb(E_dt),   256, 0, stream>>>(x_data,  ei_dt,   ei_dt   + E_dt,   E_dt,   aggD_t);
    scatter_add_k<12><<<nb(E_devt), 256, 0, stream>>>(x_dev,   ei_devt, ei_devt + E_devt, E_devt, aggDev_t);
    scatter_add_k<12><<<nb(E_to),   256, 0, stream>>>(x_tasks, ei_to,   ei_to   + E_to,   E_to,   aggTo);
    scatter_add_k<12><<<nb(E_from), 256, 0, stream>>>(x_tasks, ei_from, ei_from + E_from, E_from, aggFrom);
    scatter_add_k<12><<<nb(E_td),   256, 0, stream>>>(x_tasks, ei_td,   ei_td   + E_td,   E_td,   aggT_d);
    scatter_add_k<12><<<nb(E_devd), 256, 0, stream>>>(x_dev,   ei_devd, ei_devd + E_devd, E_devd, aggDev_d);
    scatter_dev_k<12><<<512, 256, 0, stream>>>(x_tasks, ei_tdev, ei_tdev + E_tdev, E_tdev, aggT_dev);
    scatter_dev_k<5> <<<512, 256, 0, stream>>>(x_data,  ei_ddev, ei_ddev + E_ddev, E_ddev, aggD_dev);

    float* out_tasks = (float*)d_out;
    float* out_data  = out_tasks + (size_t)NT * 16;
    float* out_dev   = out_data  + (size_t)ND * 16;

    finalize_tasks_k<<<(NT + 255) / 256, 256, 0, stream>>>(
        aggD_t, aggDev_t, aggTo, aggFrom, x_tasks,
        W_rel5, W_rel12, b_rel, W_root12, ln_g, ln_b, out_tasks, NT);
    finalize_data_k<<<(ND + 255) / 256, 256, 0, stream>>>(
        aggT_d, aggDev_d, x_data,
        W_rel12, W_root5, b_rel, ln_g, ln_b, out_data, ND);
    finalize_dev_k<<<1, 64, 0, stream>>>(
        aggT_dev, aggD_dev, x_dev,
        W_rel12, W_rel5, b_rel, W_root12, ln_g, ln_b, out_dev, NDEV);
}

// Round 2
// 828.818 us; speedup vs baseline: 3.5516x; 3.5516x over previous
//
#include <hip/hip_runtime.h>

#define LRELU(v) ((v) >= 0.0f ? (v) : 0.01f * (v))

#define NPB 1024      // destination nodes per bucket (shift = 10)
#define EPB 8192      // edges per partition block

// ---------------------------------------------------------------------------
// Pass 1: partition edges by dst bucket. part entry = (src << 10) | (dst & 1023)
// Global atomics: one int per (block, nonempty bucket).
// ---------------------------------------------------------------------------
__global__ __launch_bounds__(256)
void partition_k(const int* __restrict__ src, const int* __restrict__ dst, int E,
                 int B, unsigned int* __restrict__ part, int cap,
                 int* __restrict__ cursor)
{
    __shared__ int hist[512];
    __shared__ int base[512];
    const int t = threadIdx.x;
    const int e0 = blockIdx.x * EPB;
    const int e1 = min(E, e0 + EPB);

    for (int i = t; i < B; i += 256) hist[i] = 0;
    __syncthreads();
    for (int e = e0 + t; e < e1; e += 256)
        atomicAdd(&hist[dst[e] >> 10], 1);
    __syncthreads();
    for (int i = t; i < B; i += 256) {
        int h = hist[i];
        base[i] = h ? atomicAdd(&cursor[i], h) : 0;
    }
    __syncthreads();
    for (int i = t; i < B; i += 256) hist[i] = 0;
    __syncthreads();
    for (int e = e0 + t; e < e1; e += 256) {
        int d = dst[e];
        int b = d >> 10;
        int r = atomicAdd(&hist[b], 1) + base[b];
        if (r < cap)
            part[(size_t)b * cap + r] =
                ((unsigned int)src[e] << 10) | (unsigned int)(d & 1023);
    }
}

// ---------------------------------------------------------------------------
// Pass 2: one workgroup per bucket; accumulate into LDS, flush coalesced.
// Fully overwrites agg[n0*F .. (n0+nn)*F) -> no global memset needed.
// ---------------------------------------------------------------------------
template<int F>
__global__ __launch_bounds__(256)
void bucket_agg_k(const unsigned int* __restrict__ part, int cap,
                  const int* __restrict__ cursor,
                  const float* __restrict__ x, float* __restrict__ agg, int N)
{
    __shared__ float acc[NPB * F];   // F=12: 48 KB, F=5: 20 KB
    const int t = threadIdx.x;
    const int b = blockIdx.x;
    const int n0 = b * NPB;
    const int nn = min(NPB, N - n0);

    for (int i = t; i < nn * F; i += 256) acc[i] = 0.0f;
    __syncthreads();

    const int cnt = min(cursor[b], cap);
    const unsigned int* p = part + (size_t)b * cap;
    for (int i = t; i < cnt; i += 256) {
        unsigned int e = p[i];
        int s  = (int)(e >> 10);
        int dl = (int)(e & 1023u);
        float* a = &acc[dl * F];
        if (F == 12) {
            const float4* xr = (const float4*)(x + (size_t)s * 12);
            float4 v0 = xr[0], v1 = xr[1], v2 = xr[2];
            atomicAdd(a + 0,  v0.x); atomicAdd(a + 1,  v0.y);
            atomicAdd(a + 2,  v0.z); atomicAdd(a + 3,  v0.w);
            atomicAdd(a + 4,  v1.x); atomicAdd(a + 5,  v1.y);
            atomicAdd(a + 6,  v1.z); atomicAdd(a + 7,  v1.w);
            atomicAdd(a + 8,  v2.x); atomicAdd(a + 9,  v2.y);
            atomicAdd(a + 10, v2.z); atomicAdd(a + 11, v2.w);
        } else {
            const float* xr = x + (size_t)s * F;
            #pragma unroll
            for (int f = 0; f < F; ++f) atomicAdd(a + f, xr[f]);
        }
    }
    __syncthreads();

    float* o = agg + (size_t)n0 * F;
    for (int i = t; i < nn * F; i += 256) o[i] = acc[i];
}

// ---------------------------------------------------------------------------
// dst = devices (8 rows): per-thread register accumulation (predicated),
// wave shuffle-reduce, LDS combine, one global-atomic flush per block.
// ---------------------------------------------------------------------------
template<int F>
__global__ __launch_bounds__(256)
void scatter_dev_k(const float* __restrict__ x, const int* __restrict__ src,
                   const int* __restrict__ dst, int E, float* __restrict__ agg)
{
    __shared__ float s_agg[8 * F];
    for (int i = threadIdx.x; i < 8 * F; i += 256) s_agg[i] = 0.0f;
    __syncthreads();

    float acc[8 * F];
    #pragma unroll
    for (int i = 0; i < 8 * F; ++i) acc[i] = 0.0f;

    const int stride = gridDim.x * blockDim.x;
    for (int e = blockIdx.x * blockDim.x + threadIdx.x; e < E; e += stride) {
        int s = src[e];
        int d = dst[e];
        float xr[F];
        const float* xp = x + (size_t)s * F;
        #pragma unroll
        for (int f = 0; f < F; ++f) xr[f] = xp[f];
        #pragma unroll
        for (int dd = 0; dd < 8; ++dd) {
            bool m = (d == dd);
            #pragma unroll
            for (int f = 0; f < F; ++f)
                acc[dd * F + f] += m ? xr[f] : 0.0f;
        }
    }

    const int lane = threadIdx.x & 63;
    #pragma unroll
    for (int i = 0; i < 8 * F; ++i) {
        float v = acc[i];
        #pragma unroll
        for (int off = 32; off; off >>= 1) v += __shfl_down(v, off);
        if (lane == 0) atomicAdd(&s_agg[i], v);   // LDS atomic
    }
    __syncthreads();
    if (threadIdx.x < 8 * F) atomicAdd(&agg[threadIdx.x], s_agg[threadIdx.x]);
}

// ---------------------------------------------------------------------------
// Finalize tasks: f[53] = [aggD(5), aggDev(12), aggTo(12), aggFrom(12), x(12)]
// ---------------------------------------------------------------------------
__global__ __launch_bounds__(256)
void finalize_tasks_k(const float* __restrict__ aggD, const float* __restrict__ aggDev,
                      const float* __restrict__ aggTo, const float* __restrict__ aggFrom,
                      const float* __restrict__ x,
                      const float* __restrict__ W_rel5, const float* __restrict__ W_rel12,
                      const float* __restrict__ b_rel, const float* __restrict__ W_root12,
                      const float* __restrict__ ln_g, const float* __restrict__ ln_b,
                      float* __restrict__ out, int N)
{
    __shared__ __align__(16) float sW[53 * 16];
    __shared__ float sb[16], sg[16], sbt[16];
    const int t = threadIdx.x;
    for (int i = t; i < 80; i += 256) sW[i] = W_rel5[i];               // W_rel5[0]
    for (int i = t; i < 192; i += 256) {
        sW[80  + i] = W_rel12[384 + i];                                // W_rel12[2]
        sW[272 + i] = W_rel12[768 + i];                                // W_rel12[4]
        sW[464 + i] = W_rel12[960 + i];                                // W_rel12[5]
        sW[656 + i] = W_root12[i] + W_root12[384 + i]
                    + W_root12[768 + i] + W_root12[960 + i];           // summed roots
    }
    if (t < 16) {
        sb[t]  = b_rel[t] + b_rel[48 + t] + b_rel[96 + t] + b_rel[112 + t];
        sg[t]  = ln_g[t];
        sbt[t] = ln_b[t];
    }
    __syncthreads();
    const int i = blockIdx.x * 256 + t;
    if (i >= N) return;

    float f[53];
    {
        const float* p = aggD + (size_t)i * 5;
        #pragma unroll
        for (int j = 0; j < 5; ++j) f[j] = p[j];
        p = aggDev + (size_t)i * 12;
        #pragma unroll
        for (int j = 0; j < 12; ++j) f[5 + j] = p[j];
        p = aggTo + (size_t)i * 12;
        #pragma unroll
        for (int j = 0; j < 12; ++j) f[17 + j] = p[j];
        p = aggFrom + (size_t)i * 12;
        #pragma unroll
        for (int j = 0; j < 12; ++j) f[29 + j] = p[j];
        p = x + (size_t)i * 12;
        #pragma unroll
        for (int j = 0; j < 12; ++j) f[41 + j] = p[j];
    }

    float acc[16];
    #pragma unroll
    for (int k = 0; k < 16; ++k) acc[k] = sb[k];
    const float4* w4 = (const float4*)sW;
    #pragma unroll
    for (int j = 0; j < 53; ++j) {
        const float fj = f[j];
        float4 w0 = w4[j * 4 + 0], w1 = w4[j * 4 + 1];
        float4 w2 = w4[j * 4 + 2], w3 = w4[j * 4 + 3];
        acc[0]  = fmaf(fj, w0.x, acc[0]);  acc[1]  = fmaf(fj, w0.y, acc[1]);
        acc[2]  = fmaf(fj, w0.z, acc[2]);  acc[3]  = fmaf(fj, w0.w, acc[3]);
        acc[4]  = fmaf(fj, w1.x, acc[4]);  acc[5]  = fmaf(fj, w1.y, acc[5]);
        acc[6]  = fmaf(fj, w1.z, acc[6]);  acc[7]  = fmaf(fj, w1.w, acc[7]);
        acc[8]  = fmaf(fj, w2.x, acc[8]);  acc[9]  = fmaf(fj, w2.y, acc[9]);
        acc[10] = fmaf(fj, w2.z, acc[10]); acc[11] = fmaf(fj, w2.w, acc[11]);
        acc[12] = fmaf(fj, w3.x, acc[12]); acc[13] = fmaf(fj, w3.y, acc[13]);
        acc[14] = fmaf(fj, w3.z, acc[14]); acc[15] = fmaf(fj, w3.w, acc[15]);
    }

    float mu = 0.0f;
    #pragma unroll
    for (int k = 0; k < 16; ++k) mu += acc[k];
    mu *= (1.0f / 16.0f);
    float var = 0.0f;
    #pragma unroll
    for (int k = 0; k < 16; ++k) { float d = acc[k] - mu; var = fmaf(d, d, var); }
    var *= (1.0f / 16.0f);
    const float r = rsqrtf(var + 1e-5f);
    float* op = out + (size_t)i * 16;
    #pragma unroll
    for (int k = 0; k < 16; ++k) {
        float v = (acc[k] - mu) * r * sg[k] + sbt[k];
        op[k] = LRELU(v);
    }
}

// ---------------------------------------------------------------------------
// Finalize data: f[29] = [aggT(12), aggDev(12), x(5)]
// ---------------------------------------------------------------------------
__global__ __launch_bounds__(256)
void finalize_data_k(const float* __restrict__ aggT, const float* __restrict__ aggDev,
                     const float* __restrict__ x,
                     const float* __restrict__ W_rel12, const float* __restrict__ W_root5,
                     const float* __restrict__ b_rel,
                     const float* __restrict__ ln_g, const float* __restrict__ ln_b,
                     float* __restrict__ out, int N)
{
    __shared__ __align__(16) float sW[29 * 16];
    __shared__ float sb[16], sg[16], sbt[16];
    const int t = threadIdx.x;
    for (int i = t; i < 192; i += 256) {
        sW[i]       = W_rel12[i];          // W_rel12[0] tasks->data
        sW[192 + i] = W_rel12[576 + i];    // W_rel12[3] devices->data
    }
    for (int i = t; i < 80; i += 256)
        sW[384 + i] = W_root5[i] + W_root5[80 + i];  // W_root5[0]+W_root5[1]
    if (t < 16) {
        sb[t]  = b_rel[16 + t] + b_rel[80 + t];
        sg[t]  = ln_g[16 + t];
        sbt[t] = ln_b[16 + t];
    }
    __syncthreads();
    const int i = blockIdx.x * 256 + t;
    if (i >= N) return;

    float f[29];
    {
        const float* p = aggT + (size_t)i * 12;
        #pragma unroll
        for (int j = 0; j < 12; ++j) f[j] = p[j];
        p = aggDev + (size_t)i * 12;
        #pragma unroll
        for (int j = 0; j < 12; ++j) f[12 + j] = p[j];
        p = x + (size_t)i * 5;
        #pragma unroll
        for (int j = 0; j < 5; ++j) f[24 + j] = p[j];
    }

    float acc[16];
    #pragma unroll
    for (int k = 0; k < 16; ++k) acc[k] = sb[k];
    const float4* w4 = (const float4*)sW;
    #pragma unroll
    for (int j = 0; j < 29; ++j) {
        const float fj = f[j];
        float4 w0 = w4[j * 4 + 0], w1 = w4[j * 4 + 1];
        float4 w2 = w4[j * 4 + 2], w3 = w4[j * 4 + 3];
        acc[0]  = fmaf(fj, w0.x, acc[0]);  acc[1]  = fmaf(fj, w0.y, acc[1]);
        acc[2]  = fmaf(fj, w0.z, acc[2]);  acc[3]  = fmaf(fj, w0.w, acc[3]);
        acc[4]  = fmaf(fj, w1.x, acc[4]);  acc[5]  = fmaf(fj, w1.y, acc[5]);
        acc[6]  = fmaf(fj, w1.z, acc[6]);  acc[7]  = fmaf(fj, w1.w, acc[7]);
        acc[8]  = fmaf(fj, w2.x, acc[8]);  acc[9]  = fmaf(fj, w2.y, acc[9]);
        acc[10] = fmaf(fj, w2.z, acc[10]); acc[11] = fmaf(fj, w2.w, acc[11]);
        acc[12] = fmaf(fj, w3.x, acc[12]); acc[13] = fmaf(fj, w3.y, acc[13]);
        acc[14] = fmaf(fj, w3.z, acc[14]); acc[15] = fmaf(fj, w3.w, acc[15]);
    }

    float mu = 0.0f;
    #pragma unroll
    for (int k = 0; k < 16; ++k) mu += acc[k];
    mu *= (1.0f / 16.0f);
    float var = 0.0f;
    #pragma unroll
    for (int k = 0; k < 16; ++k) { float d = acc[k] - mu; var = fmaf(d, d, var); }
    var *= (1.0f / 16.0f);
    const float r = rsqrtf(var + 1e-5f);
    float* op = out + (size_t)i * 16;
    #pragma unroll
    for (int k = 0; k < 16; ++k) {
        float v = (acc[k] - mu) * r * sg[k] + sbt[k];
        op[k] = LRELU(v);
    }
}

// ---------------------------------------------------------------------------
// Finalize devices (8 rows, trivial)
// ---------------------------------------------------------------------------
__global__ void finalize_dev_k(const float* __restrict__ aggT, const float* __restrict__ aggD,
                               const float* __restrict__ x,
                               const float* __restrict__ W_rel12, const float* __restrict__ W_rel5,
                               const float* __restrict__ b_rel, const float* __restrict__ W_root12,
                               const float* __restrict__ ln_g, const float* __restrict__ ln_b,
                               float* __restrict__ out, int N)
{
    int i = threadIdx.x;
    if (i >= N) return;
    float acc[16];
    #pragma unroll
    for (int k = 0; k < 16; ++k) acc[k] = b_rel[32 + k] + b_rel[64 + k];
    #pragma unroll
    for (int j = 0; j < 12; ++j) {                       // aggT @ W_rel12[1]
        float fj = aggT[i * 12 + j];
        #pragma unroll
        for (int k = 0; k < 16; ++k) acc[k] = fmaf(fj, W_rel12[192 + j * 16 + k], acc[k]);
    }
    #pragma unroll
    for (int j = 0; j < 5; ++j) {                        // aggD @ W_rel5[1]
        float fj = aggD[i * 5 + j];
        #pragma unroll
        for (int k = 0; k < 16; ++k) acc[k] = fmaf(fj, W_rel5[80 + j * 16 + k], acc[k]);
    }
    #pragma unroll
    for (int j = 0; j < 12; ++j) {                       // x @ (W_root12[1]+W_root12[3])
        float fj = x[i * 12 + j];
        #pragma unroll
        for (int k = 0; k < 16; ++k)
            acc[k] = fmaf(fj, W_root12[192 + j * 16 + k] + W_root12[576 + j * 16 + k], acc[k]);
    }
    float mu = 0.0f;
    #pragma unroll
    for (int k = 0; k < 16; ++k) mu += acc[k];
    mu *= (1.0f / 16.0f);
    float var = 0.0f;
    #pragma unroll
    for (int k = 0; k < 16; ++k) { float d = acc[k] - mu; var = fmaf(d, d, var); }
    var *= (1.0f / 16.0f);
    const float r = rsqrtf(var + 1e-5f);
    #pragma unroll
    for (int k = 0; k < 16; ++k) {
        float v = (acc[k] - mu) * r * ln_g[32 + k] + ln_b[32 + k];
        out[i * 16 + k] = LRELU(v);
    }
}

// ---------------------------------------------------------------------------
extern "C" void kernel_launch(void* const* d_in, const int* in_sizes, int n_in,
                              void* d_out, int out_size, void* d_ws, size_t ws_size,
                              hipStream_t stream)
{
    const float* x_tasks = (const float*)d_in[0];
    const float* x_data  = (const float*)d_in[1];
    const float* x_dev   = (const float*)d_in[2];
    const int* ei_dt    = (const int*)d_in[3];   // data -> tasks
    const int* ei_td    = (const int*)d_in[4];   // tasks -> data
    const int* ei_tdev  = (const int*)d_in[5];   // tasks -> devices
    const int* ei_devt  = (const int*)d_in[6];   // devices -> tasks
    const int* ei_ddev  = (const int*)d_in[7];   // data -> devices
    const int* ei_devd  = (const int*)d_in[8];   // devices -> data
    const int* ei_to    = (const int*)d_in[9];   // tt_to
    const int* ei_from  = (const int*)d_in[10];  // tt_from
    const float* W_rel5   = (const float*)d_in[11];
    const float* W_rel12  = (const float*)d_in[12];
    const float* b_rel    = (const float*)d_in[13];
    const float* W_root5  = (const float*)d_in[14];
    const float* W_root12 = (const float*)d_in[15];
    const float* ln_g     = (const float*)d_in[16];
    const float* ln_b     = (const float*)d_in[17];

    const int NT   = in_sizes[0] / 12;
    const int ND   = in_sizes[1] / 5;
    const int NDEV = in_sizes[2] / 12;
    const int E_dt   = in_sizes[3]  / 2;
    const int E_td   = in_sizes[4]  / 2;
    const int E_tdev = in_sizes[5]  / 2;
    const int E_devt = in_sizes[6]  / 2;
    const int E_ddev = in_sizes[7]  / 2;
    const int E_devd = in_sizes[8]  / 2;
    const int E_to   = in_sizes[9]  / 2;
    const int E_from = in_sizes[10] / 2;

    const int B_t = (NT + NPB - 1) / NPB;   // 391 task buckets
    const int B_d = (ND + NPB - 1) / NPB;   // 196 data buckets

    // per-relation bucket capacity: mean + slack (>=5 sigma for all relations)
    auto capf = [](int E, int B) {
        int mean = E / B + 1;
        int slack = mean / 8; if (slack < 512) slack = 512;
        return mean + slack;
    };
    const int cap_dt   = capf(E_dt,   B_t);
    const int cap_devt = capf(E_devt, B_t);
    const int cap_to   = capf(E_to,   B_t);
    const int cap_from = capf(E_from, B_t);
    const int cap_td   = capf(E_td,   B_d);
    const int cap_devd = capf(E_devd, B_d);

    // ---- workspace layout (floats / ints) ----
    float* ws = (float*)d_ws;
    size_t o = 0;
    int* c_dt   = (int*)(ws + o); o += 512;
    int* c_devt = (int*)(ws + o); o += 512;
    int* c_to   = (int*)(ws + o); o += 512;
    int* c_from = (int*)(ws + o); o += 512;
    int* c_td   = (int*)(ws + o); o += 512;
    int* c_devd = (int*)(ws + o); o += 512;
    float* aggT_dev = ws + o; o += 96;
    float* aggD_dev = ws + o; o += 48;
    const size_t zero_bytes = o * sizeof(float);   // only this region needs zeroing

    float* aggD_t   = ws + o; o += (size_t)NT * 5;
    float* aggDev_t = ws + o; o += (size_t)NT * 12;
    float* aggTo    = ws + o; o += (size_t)NT * 12;
    float* aggFrom  = ws + o; o += (size_t)NT * 12;
    float* aggT_d   = ws + o; o += (size_t)ND * 12;
    float* aggDev_d = ws + o; o += (size_t)ND * 12;
    unsigned int* part = (unsigned int*)(ws + o);  // shared partition buffer (reused)

    hipMemsetAsync(d_ws, 0, zero_bytes, stream);

    auto npb = [](int e) { return (e + EPB - 1) / EPB; };

    // dst = tasks relations
    partition_k<<<npb(E_dt), 256, 0, stream>>>(ei_dt, ei_dt + E_dt, E_dt, B_t, part, cap_dt, c_dt);
    bucket_agg_k<5><<<B_t, 256, 0, stream>>>(part, cap_dt, c_dt, x_data, aggD_t, NT);

    partition_k<<<npb(E_devt), 256, 0, stream>>>(ei_devt, ei_devt + E_devt, E_devt, B_t, part, cap_devt, c_devt);
    bucket_agg_k<12><<<B_t, 256, 0, stream>>>(part, cap_devt, c_devt, x_dev, aggDev_t, NT);

    partition_k<<<npb(E_to), 256, 0, stream>>>(ei_to, ei_to + E_to, E_to, B_t, part, cap_to, c_to);
    bucket_agg_k<12><<<B_t, 256, 0, stream>>>(part, cap_to, c_to, x_tasks, aggTo, NT);

    partition_k<<<npb(E_from), 256, 0, stream>>>(ei_from, ei_from + E_from, E_from, B_t, part, cap_from, c_from);
    bucket_agg_k<12><<<B_t, 256, 0, stream>>>(part, cap_from, c_from, x_tasks, aggFrom, NT);

    // dst = data relations
    partition_k<<<npb(E_td), 256, 0, stream>>>(ei_td, ei_td + E_td, E_td, B_d, part, cap_td, c_td);
    bucket_agg_k<12><<<B_d, 256, 0, stream>>>(part, cap_td, c_td, x_tasks, aggT_d, ND);

    partition_k<<<npb(E_devd), 256, 0, stream>>>(ei_devd, ei_devd + E_devd, E_devd, B_d, part, cap_devd, c_devd);
    bucket_agg_k<12><<<B_d, 256, 0, stream>>>(part, cap_devd, c_devd, x_dev, aggDev_d, ND);

    // dst = devices relations (register accumulation)
    scatter_dev_k<12><<<128, 256, 0, stream>>>(x_tasks, ei_tdev, ei_tdev + E_tdev, E_tdev, aggT_dev);
    scatter_dev_k<5> <<<128, 256, 0, stream>>>(x_data,  ei_ddev, ei_ddev + E_ddev, E_ddev, aggD_dev);

    float* out_tasks = (float*)d_out;
    float* out_data  = out_tasks + (size_t)NT * 16;
    float* out_dev   = out_data  + (size_t)ND * 16;

    finalize_tasks_k<<<(NT + 255) / 256, 256, 0, stream>>>(
        aggD_t, aggDev_t, aggTo, aggFrom, x_tasks,
        W_rel5, W_rel12, b_rel, W_root12, ln_g, ln_b, out_tasks, NT);
    finalize_data_k<<<(ND + 255) / 256, 256, 0, stream>>>(
        aggT_d, aggDev_d, x_data,
        W_rel12, W_root5, b_rel, ln_g, ln_b, out_data, ND);
    finalize_dev_k<<<1, 64, 0, stream>>>(
        aggT_dev, aggD_dev, x_dev,
        W_rel12, W_rel5, b_rel, W_root12, ln_g, ln_b, out_dev, NDEV);
}

// Round 3
// 679.343 us; speedup vs baseline: 4.3331x; 1.2200x over previous
//
#include <hip/hip_runtime.h>

#define LRELU(v) ((v) >= 0.0f ? (v) : 0.01f * (v))
#define EPB 8192

// ===========================================================================
// Fused partition: bucket all 6 node-destination relations by dst bucket.
// part entry = (src << shift) | (dst & mask). One kernel, 6 descriptors.
// ===========================================================================
struct PartDesc {
    const int* src; const int* dst;
    unsigned int* part; int* cursor;
    int E, B, cap, shift, chunk0;
};
struct PartArgs { PartDesc r[6]; };

__global__ __launch_bounds__(256)
void partition_all_k(PartArgs a)
{
    __shared__ int hist[1600];
    __shared__ int base[1600];
    const int bid = blockIdx.x;
    int ri = 0;
    #pragma unroll
    for (int k = 1; k < 6; ++k) if (bid >= a.r[k].chunk0) ri = k;
    const PartDesc d = a.r[ri];
    const int t = threadIdx.x;
    const int e0 = (bid - d.chunk0) * EPB;
    const int e1 = min(d.E, e0 + EPB);
    const int B = d.B, sh = d.shift;
    const unsigned mask = (1u << sh) - 1u;

    for (int i = t; i < B; i += 256) hist[i] = 0;
    __syncthreads();
    for (int e = e0 + t; e < e1; e += 256)
        atomicAdd(&hist[d.dst[e] >> sh], 1);
    __syncthreads();
    for (int i = t; i < B; i += 256) {
        int h = hist[i];
        base[i] = h ? atomicAdd(&d.cursor[i], h) : 0;
        hist[i] = 0;
    }
    __syncthreads();
    for (int e = e0 + t; e < e1; e += 256) {
        int dd = d.dst[e];
        int b = dd >> sh;
        int r = atomicAdd(&hist[b], 1) + base[b];
        if (r < d.cap)
            d.part[(size_t)b * d.cap + r] =
                ((unsigned)d.src[e] << sh) | ((unsigned)dd & mask);
    }
}

// ===========================================================================
// Gather / LDS-accumulate helpers
// ===========================================================================
template<int F>
__device__ __forceinline__ void loadrow(const float* __restrict__ x, unsigned s, float* v) {
    const float* p = x + (size_t)s * F;
    #pragma unroll
    for (int f = 0; f < F; ++f) v[f] = p[f];
}
template<>
__device__ __forceinline__ void loadrow<12>(const float* __restrict__ x, unsigned s, float* v) {
    const float4* p = (const float4*)(x + (size_t)s * 12);   // rows are 48B: 16B-aligned
    float4 a = p[0], b = p[1], c = p[2];
    v[0]=a.x; v[1]=a.y; v[2]=a.z; v[3]=a.w;
    v[4]=b.x; v[5]=b.y; v[6]=b.z; v[7]=b.w;
    v[8]=c.x; v[9]=c.y; v[10]=c.z; v[11]=c.w;
}
template<int F>
__device__ __forceinline__ void addrow(float* a, const float* v) {
    #pragma unroll
    for (int f = 0; f < F; ++f) atomicAdd(a + f, v[f]);      // ds_add_f32
}

// 4x-unrolled edge loop: 4 part entries + all gathers in flight before any add.
template<int F, int STRIDE, int BASE, int SHIFT>
__device__ __forceinline__
void agg_rel(const unsigned* __restrict__ p, int cnt, const float* __restrict__ x,
             float* acc, int t)
{
    constexpr unsigned MASK = (1u << SHIFT) - 1u;
    int i = t;
    for (; i + 768 < cnt; i += 1024) {
        unsigned e0 = p[i], e1 = p[i + 256], e2 = p[i + 512], e3 = p[i + 768];
        float v0[F], v1[F], v2[F], v3[F];
        loadrow<F>(x, e0 >> SHIFT, v0);
        loadrow<F>(x, e1 >> SHIFT, v1);
        loadrow<F>(x, e2 >> SHIFT, v2);
        loadrow<F>(x, e3 >> SHIFT, v3);
        addrow<F>(acc + (e0 & MASK) * STRIDE + BASE, v0);
        addrow<F>(acc + (e1 & MASK) * STRIDE + BASE, v1);
        addrow<F>(acc + (e2 & MASK) * STRIDE + BASE, v2);
        addrow<F>(acc + (e3 & MASK) * STRIDE + BASE, v3);
    }
    for (; i < cnt; i += 256) {
        unsigned e = p[i];
        float v[F];
        loadrow<F>(x, e >> SHIFT, v);
        addrow<F>(acc + (e & MASK) * STRIDE + BASE, v);
    }
}

// dot(f, sW[NFx16]) + bias -> LayerNorm -> leaky-relu -> store
template<int NF>
__device__ __forceinline__
void dot_ln_store(const float* __restrict__ f, const float* __restrict__ sW,
                  const float* __restrict__ sb, const float* __restrict__ sg,
                  const float* __restrict__ sbt, float* __restrict__ op)
{
    float o[16];
    #pragma unroll
    for (int k = 0; k < 16; ++k) o[k] = sb[k];
    const float4* w4 = (const float4*)sW;
    #pragma unroll
    for (int j = 0; j < NF; ++j) {
        const float fj = f[j];
        float4 w0 = w4[j*4+0], w1 = w4[j*4+1], w2 = w4[j*4+2], w3 = w4[j*4+3];
        o[0] =fmaf(fj,w0.x,o[0]);  o[1] =fmaf(fj,w0.y,o[1]);
        o[2] =fmaf(fj,w0.z,o[2]);  o[3] =fmaf(fj,w0.w,o[3]);
        o[4] =fmaf(fj,w1.x,o[4]);  o[5] =fmaf(fj,w1.y,o[5]);
        o[6] =fmaf(fj,w1.z,o[6]);  o[7] =fmaf(fj,w1.w,o[7]);
        o[8] =fmaf(fj,w2.x,o[8]);  o[9] =fmaf(fj,w2.y,o[9]);
        o[10]=fmaf(fj,w2.z,o[10]); o[11]=fmaf(fj,w2.w,o[11]);
        o[12]=fmaf(fj,w3.x,o[12]); o[13]=fmaf(fj,w3.y,o[13]);
        o[14]=fmaf(fj,w3.z,o[14]); o[15]=fmaf(fj,w3.w,o[15]);
    }
    float mu = 0.0f;
    #pragma unroll
    for (int k = 0; k < 16; ++k) mu += o[k];
    mu *= 0.0625f;
    float var = 0.0f;
    #pragma unroll
    for (int k = 0; k < 16; ++k) { float d = o[k] - mu; var = fmaf(d, d, var); }
    var *= 0.0625f;
    const float r = rsqrtf(var + 1e-5f);
    #pragma unroll
    for (int k = 0; k < 16; ++k) {
        float v = (o[k] - mu) * r * sg[k] + sbt[k];
        op[k] = LRELU(v);
    }
}

// ===========================================================================
// Fused aggregate + finalize for tasks (NPB=256, acc stride 41) and
// data (NPB=512, acc stride 25 to break bank-conflict power-of-2).
// Blocks [0,Bt) = tasks, [Bt, Bt+Bd) = data.
// ===========================================================================
struct FinArgs {
    const unsigned *p_dt, *p_devt, *p_to, *p_from, *p_td, *p_devd;
    const int *c_dt, *c_devt, *c_to, *c_from, *c_td, *c_devd;
    int cap_dt, cap_devt, cap_to, cap_from, cap_td, cap_devd;
    const float *x_tasks, *x_data, *x_dev;
    const float *W_rel5, *W_rel12, *b_rel, *W_root5, *W_root12, *ln_g, *ln_b;
    float *out_tasks, *out_data;
    int NT, ND, Bt;
};

__global__ __launch_bounds__(256)
void agg_finalize_k(FinArgs A)
{
    __shared__ __align__(16) float lds[13312];   // 53248 B -> 3 blocks/CU
    const int t = threadIdx.x;

    if ((int)blockIdx.x < A.Bt) {
        // ------------------ tasks: f[53], acc 256 x stride 41 ------------------
        float* sW  = lds;            // 848 floats (53 rows x 16)
        float* sb  = lds + 848;
        float* sg  = lds + 864;
        float* sbt = lds + 880;
        float* acc = lds + 896;      // 256*41 = 10496
        const int b  = blockIdx.x;
        const int n0 = b << 8;
        const int nn = min(256, A.NT - n0);
        for (int i = t; i < 80; i += 256) sW[i] = A.W_rel5[i];            // W_rel5[0]
        for (int i = t; i < 192; i += 256) {
            sW[80  + i] = A.W_rel12[384 + i];                             // W_rel12[2]
            sW[272 + i] = A.W_rel12[768 + i];                             // W_rel12[4]
            sW[464 + i] = A.W_rel12[960 + i];                             // W_rel12[5]
            sW[656 + i] = A.W_root12[i] + A.W_root12[384 + i]
                        + A.W_root12[768 + i] + A.W_root12[960 + i];
        }
        if (t < 16) {
            sb[t]  = A.b_rel[t] + A.b_rel[48 + t] + A.b_rel[96 + t] + A.b_rel[112 + t];
            sg[t]  = A.ln_g[t];
            sbt[t] = A.ln_b[t];
        }
        for (int i = t; i < 256 * 41; i += 256) acc[i] = 0.0f;
        __syncthreads();

        agg_rel<5, 41, 0, 8>(A.p_dt   + (size_t)b * A.cap_dt,   min(A.c_dt[b],   A.cap_dt),   A.x_data,  acc, t);
        agg_rel<12,41, 5, 8>(A.p_devt + (size_t)b * A.cap_devt, min(A.c_devt[b], A.cap_devt), A.x_dev,   acc, t);
        agg_rel<12,41,17, 8>(A.p_to   + (size_t)b * A.cap_to,   min(A.c_to[b],   A.cap_to),   A.x_tasks, acc, t);
        agg_rel<12,41,29, 8>(A.p_from + (size_t)b * A.cap_from, min(A.c_from[b], A.cap_from), A.x_tasks, acc, t);
        __syncthreads();

        if (t < nn) {
            float f[53];
            #pragma unroll
            for (int j = 0; j < 41; ++j) f[j] = acc[t * 41 + j];
            const float* xr = A.x_tasks + (size_t)(n0 + t) * 12;
            #pragma unroll
            for (int j = 0; j < 12; ++j) f[41 + j] = xr[j];
            dot_ln_store<53>(f, sW, sb, sg, sbt, A.out_tasks + (size_t)(n0 + t) * 16);
        }
    } else {
        // ------------------ data: f[29], acc 512 x stride 25 ------------------
        float* sW  = lds;            // 464 floats (29 rows x 16)
        float* sb  = lds + 464;
        float* sg  = lds + 480;
        float* sbt = lds + 496;
        float* acc = lds + 512;      // 512*25 = 12800
        const int b  = blockIdx.x - A.Bt;
        const int n0 = b << 9;
        for (int i = t; i < 192; i += 256) {
            sW[i]       = A.W_rel12[i];                                   // W_rel12[0]
            sW[192 + i] = A.W_rel12[576 + i];                             // W_rel12[3]
        }
        for (int i = t; i < 80; i += 256)
            sW[384 + i] = A.W_root5[i] + A.W_root5[80 + i];
        if (t < 16) {
            sb[t]  = A.b_rel[16 + t] + A.b_rel[80 + t];
            sg[t]  = A.ln_g[16 + t];
            sbt[t] = A.ln_b[16 + t];
        }
        for (int i = t; i < 512 * 25; i += 256) acc[i] = 0.0f;
        __syncthreads();

        agg_rel<12,25, 0, 9>(A.p_td   + (size_t)b * A.cap_td,   min(A.c_td[b],   A.cap_td),   A.x_tasks, acc, t);
        agg_rel<12,25,12, 9>(A.p_devd + (size_t)b * A.cap_devd, min(A.c_devd[b], A.cap_devd), A.x_dev,   acc, t);
        __syncthreads();

        for (int n = t; n < 512; n += 256) {
            const int node = n0 + n;
            if (node >= A.ND) break;
            float f[29];
            #pragma unroll
            for (int j = 0; j < 24; ++j) f[j] = acc[n * 25 + j];
            const float* xr = A.x_data + (size_t)node * 5;
            #pragma unroll
            for (int j = 0; j < 5; ++j) f[24 + j] = xr[j];
            dot_ln_store<29>(f, sW, sb, sg, sbt, A.out_data + (size_t)node * 16);
        }
    }
}

// ===========================================================================
// dst = devices (8 rows): register accumulation + shuffle reduce
// ===========================================================================
template<int F>
__global__ __launch_bounds__(256)
void scatter_dev_k(const float* __restrict__ x, const int* __restrict__ src,
                   const int* __restrict__ dst, int E, float* __restrict__ agg)
{
    __shared__ float s_agg[8 * F];
    for (int i = threadIdx.x; i < 8 * F; i += 256) s_agg[i] = 0.0f;
    __syncthreads();

    float acc[8 * F];
    #pragma unroll
    for (int i = 0; i < 8 * F; ++i) acc[i] = 0.0f;

    const int stride = gridDim.x * blockDim.x;
    for (int e = blockIdx.x * blockDim.x + threadIdx.x; e < E; e += stride) {
        int s = src[e];
        int d = dst[e];
        float xr[F];
        loadrow<F>(x, (unsigned)s, xr);
        #pragma unroll
        for (int dd = 0; dd < 8; ++dd) {
            bool m = (d == dd);
            #pragma unroll
            for (int f = 0; f < F; ++f)
                acc[dd * F + f] += m ? xr[f] : 0.0f;
        }
    }

    const int lane = threadIdx.x & 63;
    #pragma unroll
    for (int i = 0; i < 8 * F; ++i) {
        float v = acc[i];
        #pragma unroll
        for (int off = 32; off; off >>= 1) v += __shfl_down(v, off);
        if (lane == 0) atomicAdd(&s_agg[i], v);
    }
    __syncthreads();
    if (threadIdx.x < 8 * F) atomicAdd(&agg[threadIdx.x], s_agg[threadIdx.x]);
}

__global__ void finalize_dev_k(const float* __restrict__ aggT, const float* __restrict__ aggD,
                               const float* __restrict__ x,
                               const float* __restrict__ W_rel12, const float* __restrict__ W_rel5,
                               const float* __restrict__ b_rel, const float* __restrict__ W_root12,
                               const float* __restrict__ ln_g, const float* __restrict__ ln_b,
                               float* __restrict__ out, int N)
{
    int i = threadIdx.x;
    if (i >= N) return;
    float acc[16];
    #pragma unroll
    for (int k = 0; k < 16; ++k) acc[k] = b_rel[32 + k] + b_rel[64 + k];
    #pragma unroll
    for (int j = 0; j < 12; ++j) {
        float fj = aggT[i * 12 + j];
        #pragma unroll
        for (int k = 0; k < 16; ++k) acc[k] = fmaf(fj, W_rel12[192 + j * 16 + k], acc[k]);
    }
    #pragma unroll
    for (int j = 0; j < 5; ++j) {
        float fj = aggD[i * 5 + j];
        #pragma unroll
        for (int k = 0; k < 16; ++k) acc[k] = fmaf(fj, W_rel5[80 + j * 16 + k], acc[k]);
    }
    #pragma unroll
    for (int j = 0; j < 12; ++j) {
        float fj = x[i * 12 + j];
        #pragma unroll
        for (int k = 0; k < 16; ++k)
            acc[k] = fmaf(fj, W_root12[192 + j * 16 + k] + W_root12[576 + j * 16 + k], acc[k]);
    }
    float mu = 0.0f;
    #pragma unroll
    for (int k = 0; k < 16; ++k) mu += acc[k];
    mu *= 0.0625f;
    float var = 0.0f;
    #pragma unroll
    for (int k = 0; k < 16; ++k) { float d = acc[k] - mu; var = fmaf(d, d, var); }
    var *= 0.0625f;
    const float r = rsqrtf(var + 1e-5f);
    #pragma unroll
    for (int k = 0; k < 16; ++k) {
        float v = (acc[k] - mu) * r * ln_g[32 + k] + ln_b[32 + k];
        out[i * 16 + k] = LRELU(v);
    }
}

// ===========================================================================
extern "C" void kernel_launch(void* const* d_in, const int* in_sizes, int n_in,
                              void* d_out, int out_size, void* d_ws, size_t ws_size,
                              hipStream_t stream)
{
    const float* x_tasks = (const float*)d_in[0];
    const float* x_data  = (const float*)d_in[1];
    const float* x_dev   = (const float*)d_in[2];
    const int* ei_dt    = (const int*)d_in[3];
    const int* ei_td    = (const int*)d_in[4];
    const int* ei_tdev  = (const int*)d_in[5];
    const int* ei_devt  = (const int*)d_in[6];
    const int* ei_ddev  = (const int*)d_in[7];
    const int* ei_devd  = (const int*)d_in[8];
    const int* ei_to    = (const int*)d_in[9];
    const int* ei_from  = (const int*)d_in[10];
    const float* W_rel5   = (const float*)d_in[11];
    const float* W_rel12  = (const float*)d_in[12];
    const float* b_rel    = (const float*)d_in[13];
    const float* W_root5  = (const float*)d_in[14];
    const float* W_root12 = (const float*)d_in[15];
    const float* ln_g     = (const float*)d_in[16];
    const float* ln_b     = (const float*)d_in[17];

    const int NT   = in_sizes[0] / 12;
    const int ND   = in_sizes[1] / 5;
    const int NDEV = in_sizes[2] / 12;
    const int E_dt   = in_sizes[3]  / 2;
    const int E_td   = in_sizes[4]  / 2;
    const int E_tdev = in_sizes[5]  / 2;
    const int E_devt = in_sizes[6]  / 2;
    const int E_ddev = in_sizes[7]  / 2;
    const int E_devd = in_sizes[8]  / 2;
    const int E_to   = in_sizes[9]  / 2;
    const int E_from = in_sizes[10] / 2;

    const int B_t = (NT + 255) / 256;    // 1563 task buckets (shift 8)
    const int B_d = (ND + 511) / 512;    // 391 data buckets (shift 9)

    auto capf = [](int E, int B) {       // mean + >=12 sigma slack
        int mean = E / B + 1;
        return mean + 256 + mean / 8;
    };
    const int cap_dt   = capf(E_dt,   B_t);
    const int cap_devt = capf(E_devt, B_t);
    const int cap_to   = capf(E_to,   B_t);
    const int cap_from = capf(E_from, B_t);
    const int cap_td   = capf(E_td,   B_d);
    const int cap_devd = capf(E_devd, B_d);

    // ---- workspace ----
    float* ws = (float*)d_ws;
    size_t o = 0;
    int* c_dt   = (int*)(ws + o); o += 1600;
    int* c_devt = (int*)(ws + o); o += 1600;
    int* c_to   = (int*)(ws + o); o += 1600;
    int* c_from = (int*)(ws + o); o += 1600;
    int* c_td   = (int*)(ws + o); o += 512;
    int* c_devd = (int*)(ws + o); o += 512;
    float* aggT_dev = ws + o; o += 96;
    float* aggD_dev = ws + o; o += 48;
    const size_t zero_bytes = o * sizeof(float);
    unsigned* p_dt   = (unsigned*)(ws + o); o += (size_t)B_t * cap_dt;
    unsigned* p_devt = (unsigned*)(ws + o); o += (size_t)B_t * cap_devt;
    unsigned* p_to   = (unsigned*)(ws + o); o += (size_t)B_t * cap_to;
    unsigned* p_from = (unsigned*)(ws + o); o += (size_t)B_t * cap_from;
    unsigned* p_td   = (unsigned*)(ws + o); o += (size_t)B_d * cap_td;
    unsigned* p_devd = (unsigned*)(ws + o); o += (size_t)B_d * cap_devd;

    hipMemsetAsync(d_ws, 0, zero_bytes, stream);

    auto nc = [](int e) { return (e + EPB - 1) / EPB; };
    PartArgs pa;
    int ch = 0;
    pa.r[0] = { ei_dt,   ei_dt   + E_dt,   p_dt,   c_dt,   E_dt,   B_t, cap_dt,   8, ch }; ch += nc(E_dt);
    pa.r[1] = { ei_devt, ei_devt + E_devt, p_devt, c_devt, E_devt, B_t, cap_devt, 8, ch }; ch += nc(E_devt);
    pa.r[2] = { ei_to,   ei_to   + E_to,   p_to,   c_to,   E_to,   B_t, cap_to,   8, ch }; ch += nc(E_to);
    pa.r[3] = { ei_from, ei_from + E_from, p_from, c_from, E_from, B_t, cap_from, 8, ch }; ch += nc(E_from);
    pa.r[4] = { ei_td,   ei_td   + E_td,   p_td,   c_td,   E_td,   B_d, cap_td,   9, ch }; ch += nc(E_td);
    pa.r[5] = { ei_devd, ei_devd + E_devd, p_devd, c_devd, E_devd, B_d, cap_devd, 9, ch }; ch += nc(E_devd);

    partition_all_k<<<ch, 256, 0, stream>>>(pa);

    scatter_dev_k<12><<<256, 256, 0, stream>>>(x_tasks, ei_tdev, ei_tdev + E_tdev, E_tdev, aggT_dev);
    scatter_dev_k<5> <<<128, 256, 0, stream>>>(x_data,  ei_ddev, ei_ddev + E_ddev, E_ddev, aggD_dev);

    float* out_tasks = (float*)d_out;
    float* out_data  = out_tasks + (size_t)NT * 16;
    float* out_dev   = out_data  + (size_t)ND * 16;

    FinArgs fa;
    fa.p_dt = p_dt; fa.p_devt = p_devt; fa.p_to = p_to; fa.p_from = p_from;
    fa.p_td = p_td; fa.p_devd = p_devd;
    fa.c_dt = c_dt; fa.c_devt = c_devt; fa.c_to = c_to; fa.c_from = c_from;
    fa.c_td = c_td; fa.c_devd = c_devd;
    fa.cap_dt = cap_dt; fa.cap_devt = cap_devt; fa.cap_to = cap_to;
    fa.cap_from = cap_from; fa.cap_td = cap_td; fa.cap_devd = cap_devd;
    fa.x_tasks = x_tasks; fa.x_data = x_data; fa.x_dev = x_dev;
    fa.W_rel5 = W_rel5; fa.W_rel12 = W_rel12; fa.b_rel = b_rel;
    fa.W_root5 = W_root5; fa.W_root12 = W_root12; fa.ln_g = ln_g; fa.ln_b = ln_b;
    fa.out_tasks = out_tasks; fa.out_data = out_data;
    fa.NT = NT; fa.ND = ND; fa.Bt = B_t;

    agg_finalize_k<<<B_t + B_d, 256, 0, stream>>>(fa);

    finalize_dev_k<<<1, 64, 0, stream>>>(
        aggT_dev, aggD_dev, x_dev,
        W_rel12, W_rel5, b_rel, W_root12, ln_g, ln_b, out_dev, NDEV);
}

// Round 4
// 646.929 us; speedup vs baseline: 4.5502x; 1.0501x over previous
//
#include <hip/hip_runtime.h>

#define LRELU(v) ((v) >= 0.0f ? (v) : 0.01f * (v))
#define EPB 8192
#define SHIFT_T 7      // tasks bucket = 128 nodes
#define SHIFT_D 8      // data bucket = 256 nodes
#define MAXB 3200

// ===========================================================================
// Fused partition: bucket all 6 node-destination relations by dst bucket.
// part entry = (src << shift) | (dst & mask).
// ===========================================================================
struct PartDesc {
    const int* src; const int* dst;
    unsigned int* part; int* cursor;
    int E, B, cap, shift, chunk0;
};
struct PartArgs { PartDesc r[6]; };

__global__ __launch_bounds__(256)
void partition_all_k(PartArgs a)
{
    __shared__ int hist[MAXB];
    __shared__ int base[MAXB];
    const int bid = blockIdx.x;
    int ri = 0;
    #pragma unroll
    for (int k = 1; k < 6; ++k) if (bid >= a.r[k].chunk0) ri = k;
    const PartDesc d = a.r[ri];
    const int t = threadIdx.x;
    const int e0 = (bid - d.chunk0) * EPB;
    const int e1 = min(d.E, e0 + EPB);
    const int B = d.B, sh = d.shift;
    const unsigned mask = (1u << sh) - 1u;

    for (int i = t; i < B; i += 256) hist[i] = 0;
    __syncthreads();
    for (int e = e0 + t; e < e1; e += 256)
        atomicAdd(&hist[d.dst[e] >> sh], 1);
    __syncthreads();
    for (int i = t; i < B; i += 256) {
        int h = hist[i];
        base[i] = h ? atomicAdd(&d.cursor[i], h) : 0;
        hist[i] = 0;
    }
    __syncthreads();
    for (int e = e0 + t; e < e1; e += 256) {
        int dd = d.dst[e];
        int b = dd >> sh;
        int r = atomicAdd(&hist[b], 1) + base[b];
        if (r < d.cap)
            d.part[(size_t)b * d.cap + r] =
                ((unsigned)d.src[e] << sh) | ((unsigned)dd & mask);
    }
}

// ===========================================================================
// Gather / LDS-accumulate helpers
// ===========================================================================
template<int F>
__device__ __forceinline__ void loadrow(const float* __restrict__ x, unsigned s, float* v) {
    const float* p = x + (size_t)s * F;
    #pragma unroll
    for (int f = 0; f < F; ++f) v[f] = p[f];
}
template<>
__device__ __forceinline__ void loadrow<12>(const float* __restrict__ x, unsigned s, float* v) {
    const float4* p = (const float4*)(x + (size_t)s * 12);   // 48B rows, 16B-aligned
    float4 a = p[0], b = p[1], c = p[2];
    v[0]=a.x; v[1]=a.y; v[2]=a.z; v[3]=a.w;
    v[4]=b.x; v[5]=b.y; v[6]=b.z; v[7]=b.w;
    v[8]=c.x; v[9]=c.y; v[10]=c.z; v[11]=c.w;
}
template<int F>
__device__ __forceinline__ void addrow(float* a, const float* v) {
    #pragma unroll
    for (int f = 0; f < F; ++f) atomicAdd(a + f, v[f]);      // ds_add_f32
}

// Pair-unrolled edge loop: one uint2 part-load feeds two gathers in flight.
template<int F, int STRIDE, int BASE, int SHIFT>
__device__ __forceinline__
void agg_rel(const unsigned* __restrict__ p, int cnt, const float* __restrict__ x,
             float* acc, int t)
{
    constexpr unsigned MASK = (1u << SHIFT) - 1u;
    int i = 2 * t;
    for (; i + 1 < cnt; i += 512) {
        uint2 e = *(const uint2*)(p + i);   // part base & cap are 8B-aligned
        float v0[F], v1[F];
        loadrow<F>(x, e.x >> SHIFT, v0);
        loadrow<F>(x, e.y >> SHIFT, v1);
        addrow<F>(acc + (e.x & MASK) * STRIDE + BASE, v0);
        addrow<F>(acc + (e.y & MASK) * STRIDE + BASE, v1);
    }
    if (i < cnt) {                          // odd tail: exactly one thread lands here
        unsigned e = p[i];
        float v[F];
        loadrow<F>(x, e >> SHIFT, v);
        addrow<F>(acc + (e & MASK) * STRIDE + BASE, v);
    }
}

// dot(f, sW[NFx16]) + bias -> LayerNorm -> leaky-relu -> store
template<int NF>
__device__ __forceinline__
void dot_ln_store(const float* __restrict__ f, const float* __restrict__ sW,
                  const float* __restrict__ sb, const float* __restrict__ sg,
                  const float* __restrict__ sbt, float* __restrict__ op)
{
    float o[16];
    #pragma unroll
    for (int k = 0; k < 16; ++k) o[k] = sb[k];
    const float4* w4 = (const float4*)sW;
    #pragma unroll
    for (int j = 0; j < NF; ++j) {
        const float fj = f[j];
        float4 w0 = w4[j*4+0], w1 = w4[j*4+1], w2 = w4[j*4+2], w3 = w4[j*4+3];
        o[0] =fmaf(fj,w0.x,o[0]);  o[1] =fmaf(fj,w0.y,o[1]);
        o[2] =fmaf(fj,w0.z,o[2]);  o[3] =fmaf(fj,w0.w,o[3]);
        o[4] =fmaf(fj,w1.x,o[4]);  o[5] =fmaf(fj,w1.y,o[5]);
        o[6] =fmaf(fj,w1.z,o[6]);  o[7] =fmaf(fj,w1.w,o[7]);
        o[8] =fmaf(fj,w2.x,o[8]);  o[9] =fmaf(fj,w2.y,o[9]);
        o[10]=fmaf(fj,w2.z,o[10]); o[11]=fmaf(fj,w2.w,o[11]);
        o[12]=fmaf(fj,w3.x,o[12]); o[13]=fmaf(fj,w3.y,o[13]);
        o[14]=fmaf(fj,w3.z,o[14]); o[15]=fmaf(fj,w3.w,o[15]);
    }
    float mu = 0.0f;
    #pragma unroll
    for (int k = 0; k < 16; ++k) mu += o[k];
    mu *= 0.0625f;
    float var = 0.0f;
    #pragma unroll
    for (int k = 0; k < 16; ++k) { float d = o[k] - mu; var = fmaf(d, d, var); }
    var *= 0.0625f;
    const float r = rsqrtf(var + 1e-5f);
    #pragma unroll
    for (int k = 0; k < 16; ++k) {
        float v = (o[k] - mu) * r * sg[k] + sbt[k];
        op[k] = LRELU(v);
    }
}

// ===========================================================================
// Fused aggregate + finalize. Tasks: NPB=128, acc stride 41 (24.6 KB LDS).
// Data: NPB=256, acc stride 25 (27.6 KB LDS). 5 blocks/CU by LDS, 4 by VGPR.
// ===========================================================================
struct FinArgs {
    const unsigned *p_dt, *p_devt, *p_to, *p_from, *p_td, *p_devd;
    const int *c_dt, *c_devt, *c_to, *c_from, *c_td, *c_devd;
    int cap_dt, cap_devt, cap_to, cap_from, cap_td, cap_devd;
    const float *x_tasks, *x_data, *x_dev;
    const float *W_rel5, *W_rel12, *b_rel, *W_root5, *W_root12, *ln_g, *ln_b;
    float *out_tasks, *out_data;
    int NT, ND, Bt;
};

__global__ __launch_bounds__(256, 4)   // cap VGPR<=128: 4 blocks/CU resident
void agg_finalize_k(FinArgs A)
{
    __shared__ __align__(16) float lds[6912];   // 27648 B
    const int t = threadIdx.x;

    if ((int)blockIdx.x < A.Bt) {
        // -------- tasks: f[53], acc 128 x stride 41 --------
        float* sW  = lds;            // 848 floats
        float* sb  = lds + 848;
        float* sg  = lds + 864;
        float* sbt = lds + 880;
        float* acc = lds + 896;      // 128*41 = 5248
        const int b  = blockIdx.x;
        const int n0 = b << SHIFT_T;
        const int nn = min(128, A.NT - n0);
        for (int i = t; i < 80; i += 256) sW[i] = A.W_rel5[i];            // W_rel5[0]
        for (int i = t; i < 192; i += 256) {
            sW[80  + i] = A.W_rel12[384 + i];                             // W_rel12[2]
            sW[272 + i] = A.W_rel12[768 + i];                             // W_rel12[4]
            sW[464 + i] = A.W_rel12[960 + i];                             // W_rel12[5]
            sW[656 + i] = A.W_root12[i] + A.W_root12[384 + i]
                        + A.W_root12[768 + i] + A.W_root12[960 + i];
        }
        if (t < 16) {
            sb[t]  = A.b_rel[t] + A.b_rel[48 + t] + A.b_rel[96 + t] + A.b_rel[112 + t];
            sg[t]  = A.ln_g[t];
            sbt[t] = A.ln_b[t];
        }
        for (int i = t; i < 128 * 41; i += 256) acc[i] = 0.0f;
        __syncthreads();

        agg_rel<5, 41, 0, SHIFT_T>(A.p_dt   + (size_t)b * A.cap_dt,   min(A.c_dt[b],   A.cap_dt),   A.x_data,  acc, t);
        agg_rel<12,41, 5, SHIFT_T>(A.p_devt + (size_t)b * A.cap_devt, min(A.c_devt[b], A.cap_devt), A.x_dev,   acc, t);
        agg_rel<12,41,17, SHIFT_T>(A.p_to   + (size_t)b * A.cap_to,   min(A.c_to[b],   A.cap_to),   A.x_tasks, acc, t);
        agg_rel<12,41,29, SHIFT_T>(A.p_from + (size_t)b * A.cap_from, min(A.c_from[b], A.cap_from), A.x_tasks, acc, t);
        __syncthreads();

        if (t < nn) {
            float f[53];
            #pragma unroll
            for (int j = 0; j < 41; ++j) f[j] = acc[t * 41 + j];
            const float* xr = A.x_tasks + (size_t)(n0 + t) * 12;
            #pragma unroll
            for (int j = 0; j < 12; ++j) f[41 + j] = xr[j];
            dot_ln_store<53>(f, sW, sb, sg, sbt, A.out_tasks + (size_t)(n0 + t) * 16);
        }
    } else {
        // -------- data: f[29], acc 256 x stride 25 --------
        float* sW  = lds;            // 464 floats
        float* sb  = lds + 464;
        float* sg  = lds + 480;
        float* sbt = lds + 496;
        float* acc = lds + 512;      // 256*25 = 6400
        const int b  = blockIdx.x - A.Bt;
        const int n0 = b << SHIFT_D;
        const int nn = min(256, A.ND - n0);
        for (int i = t; i < 192; i += 256) {
            sW[i]       = A.W_rel12[i];                                   // W_rel12[0]
            sW[192 + i] = A.W_rel12[576 + i];                             // W_rel12[3]
        }
        for (int i = t; i < 80; i += 256)
            sW[384 + i] = A.W_root5[i] + A.W_root5[80 + i];
        if (t < 16) {
            sb[t]  = A.b_rel[16 + t] + A.b_rel[80 + t];
            sg[t]  = A.ln_g[16 + t];
            sbt[t] = A.ln_b[16 + t];
        }
        for (int i = t; i < 256 * 25; i += 256) acc[i] = 0.0f;
        __syncthreads();

        agg_rel<12,25, 0, SHIFT_D>(A.p_td   + (size_t)b * A.cap_td,   min(A.c_td[b],   A.cap_td),   A.x_tasks, acc, t);
        agg_rel<12,25,12, SHIFT_D>(A.p_devd + (size_t)b * A.cap_devd, min(A.c_devd[b], A.cap_devd), A.x_dev,   acc, t);
        __syncthreads();

        if (t < nn) {
            float f[29];
            #pragma unroll
            for (int j = 0; j < 24; ++j) f[j] = acc[t * 25 + j];
            const float* xr = A.x_data + (size_t)(n0 + t) * 5;
            #pragma unroll
            for (int j = 0; j < 5; ++j) f[24 + j] = xr[j];
            dot_ln_store<29>(f, sW, sb, sg, sbt, A.out_data + (size_t)(n0 + t) * 16);
        }
    }
}

// ===========================================================================
// dst = devices (8 rows): register accumulation + shuffle reduce
// ===========================================================================
template<int F>
__global__ __launch_bounds__(256)
void scatter_dev_k(const float* __restrict__ x, const int* __restrict__ src,
                   const int* __restrict__ dst, int E, float* __restrict__ agg)
{
    __shared__ float s_agg[8 * F];
    for (int i = threadIdx.x; i < 8 * F; i += 256) s_agg[i] = 0.0f;
    __syncthreads();

    float acc[8 * F];
    #pragma unroll
    for (int i = 0; i < 8 * F; ++i) acc[i] = 0.0f;

    const int stride = gridDim.x * blockDim.x;
    for (int e = blockIdx.x * blockDim.x + threadIdx.x; e < E; e += stride) {
        int s = src[e];
        int d = dst[e];
        float xr[F];
        loadrow<F>(x, (unsigned)s, xr);
        #pragma unroll
        for (int dd = 0; dd < 8; ++dd) {
            bool m = (d == dd);
            #pragma unroll
            for (int f = 0; f < F; ++f)
                acc[dd * F + f] += m ? xr[f] : 0.0f;
        }
    }

    const int lane = threadIdx.x & 63;
    #pragma unroll
    for (int i = 0; i < 8 * F; ++i) {
        float v = acc[i];
        #pragma unroll
        for (int off = 32; off; off >>= 1) v += __shfl_down(v, off);
        if (lane == 0) atomicAdd(&s_agg[i], v);
    }
    __syncthreads();
    if (threadIdx.x < 8 * F) atomicAdd(&agg[threadIdx.x], s_agg[threadIdx.x]);
}

__global__ void finalize_dev_k(const float* __restrict__ aggT, const float* __restrict__ aggD,
                               const float* __restrict__ x,
                               const float* __restrict__ W_rel12, const float* __restrict__ W_rel5,
                               const float* __restrict__ b_rel, const float* __restrict__ W_root12,
                               const float* __restrict__ ln_g, const float* __restrict__ ln_b,
                               float* __restrict__ out, int N)
{
    int i = threadIdx.x;
    if (i >= N) return;
    float acc[16];
    #pragma unroll
    for (int k = 0; k < 16; ++k) acc[k] = b_rel[32 + k] + b_rel[64 + k];
    #pragma unroll
    for (int j = 0; j < 12; ++j) {
        float fj = aggT[i * 12 + j];
        #pragma unroll
        for (int k = 0; k < 16; ++k) acc[k] = fmaf(fj, W_rel12[192 + j * 16 + k], acc[k]);
    }
    #pragma unroll
    for (int j = 0; j < 5; ++j) {
        float fj = aggD[i * 5 + j];
        #pragma unroll
        for (int k = 0; k < 16; ++k) acc[k] = fmaf(fj, W_rel5[80 + j * 16 + k], acc[k]);
    }
    #pragma unroll
    for (int j = 0; j < 12; ++j) {
        float fj = x[i * 12 + j];
        #pragma unroll
        for (int k = 0; k < 16; ++k)
            acc[k] = fmaf(fj, W_root12[192 + j * 16 + k] + W_root12[576 + j * 16 + k], acc[k]);
    }
    float mu = 0.0f;
    #pragma unroll
    for (int k = 0; k < 16; ++k) mu += acc[k];
    mu *= 0.0625f;
    float var = 0.0f;
    #pragma unroll
    for (int k = 0; k < 16; ++k) { float d = acc[k] - mu; var = fmaf(d, d, var); }
    var *= 0.0625f;
    const float r = rsqrtf(var + 1e-5f);
    #pragma unroll
    for (int k = 0; k < 16; ++k) {
        float v = (acc[k] - mu) * r * ln_g[32 + k] + ln_b[32 + k];
        out[i * 16 + k] = LRELU(v);
    }
}

// ===========================================================================
extern "C" void kernel_launch(void* const* d_in, const int* in_sizes, int n_in,
                              void* d_out, int out_size, void* d_ws, size_t ws_size,
                              hipStream_t stream)
{
    const float* x_tasks = (const float*)d_in[0];
    const float* x_data  = (const float*)d_in[1];
    const float* x_dev   = (const float*)d_in[2];
    const int* ei_dt    = (const int*)d_in[3];
    const int* ei_td    = (const int*)d_in[4];
    const int* ei_tdev  = (const int*)d_in[5];
    const int* ei_devt  = (const int*)d_in[6];
    const int* ei_ddev  = (const int*)d_in[7];
    const int* ei_devd  = (const int*)d_in[8];
    const int* ei_to    = (const int*)d_in[9];
    const int* ei_from  = (const int*)d_in[10];
    const float* W_rel5   = (const float*)d_in[11];
    const float* W_rel12  = (const float*)d_in[12];
    const float* b_rel    = (const float*)d_in[13];
    const float* W_root5  = (const float*)d_in[14];
    const float* W_root12 = (const float*)d_in[15];
    const float* ln_g     = (const float*)d_in[16];
    const float* ln_b     = (const float*)d_in[17];

    const int NT   = in_sizes[0] / 12;
    const int ND   = in_sizes[1] / 5;
    const int NDEV = in_sizes[2] / 12;
    const int E_dt   = in_sizes[3]  / 2;
    const int E_td   = in_sizes[4]  / 2;
    const int E_tdev = in_sizes[5]  / 2;
    const int E_devt = in_sizes[6]  / 2;
    const int E_ddev = in_sizes[7]  / 2;
    const int E_devd = in_sizes[8]  / 2;
    const int E_to   = in_sizes[9]  / 2;
    const int E_from = in_sizes[10] / 2;

    const int B_t = (NT + 127) / 128;    // 3125 task buckets (shift 7)
    const int B_d = (ND + 255) / 256;    // 782 data buckets (shift 8)

    auto capf = [](int E, int B) {       // mean + generous slack, even for uint2
        int mean = E / B + 1;
        int c = mean + 256 + mean / 8;
        return (c + 1) & ~1;
    };
    const int cap_dt   = capf(E_dt,   B_t);
    const int cap_devt = capf(E_devt, B_t);
    const int cap_to   = capf(E_to,   B_t);
    const int cap_from = capf(E_from, B_t);
    const int cap_td   = capf(E_td,   B_d);
    const int cap_devd = capf(E_devd, B_d);

    // ---- workspace ----
    float* ws = (float*)d_ws;
    size_t o = 0;
    int* c_dt   = (int*)(ws + o); o += MAXB;
    int* c_devt = (int*)(ws + o); o += MAXB;
    int* c_to   = (int*)(ws + o); o += MAXB;
    int* c_from = (int*)(ws + o); o += MAXB;
    int* c_td   = (int*)(ws + o); o += 800;
    int* c_devd = (int*)(ws + o); o += 800;
    float* aggT_dev = ws + o; o += 96;
    float* aggD_dev = ws + o; o += 48;
    const size_t zero_bytes = o * sizeof(float);
    o = (o + 1) & ~(size_t)1;                       // 8B-align part buffers
    unsigned* p_dt   = (unsigned*)(ws + o); o += (size_t)B_t * cap_dt;
    unsigned* p_devt = (unsigned*)(ws + o); o += (size_t)B_t * cap_devt;
    unsigned* p_to   = (unsigned*)(ws + o); o += (size_t)B_t * cap_to;
    unsigned* p_from = (unsigned*)(ws + o); o += (size_t)B_t * cap_from;
    unsigned* p_td   = (unsigned*)(ws + o); o += (size_t)B_d * cap_td;
    unsigned* p_devd = (unsigned*)(ws + o); o += (size_t)B_d * cap_devd;

    hipMemsetAsync(d_ws, 0, zero_bytes, stream);

    auto nc = [](int e) { return (e + EPB - 1) / EPB; };
    PartArgs pa;
    int ch = 0;
    pa.r[0] = { ei_dt,   ei_dt   + E_dt,   p_dt,   c_dt,   E_dt,   B_t, cap_dt,   SHIFT_T, ch }; ch += nc(E_dt);
    pa.r[1] = { ei_devt, ei_devt + E_devt, p_devt, c_devt, E_devt, B_t, cap_devt, SHIFT_T, ch }; ch += nc(E_devt);
    pa.r[2] = { ei_to,   ei_to   + E_to,   p_to,   c_to,   E_to,   B_t, cap_to,   SHIFT_T, ch }; ch += nc(E_to);
    pa.r[3] = { ei_from, ei_from + E_from, p_from, c_from, E_from, B_t, cap_from, SHIFT_T, ch }; ch += nc(E_from);
    pa.r[4] = { ei_td,   ei_td   + E_td,   p_td,   c_td,   E_td,   B_d, cap_td,   SHIFT_D, ch }; ch += nc(E_td);
    pa.r[5] = { ei_devd, ei_devd + E_devd, p_devd, c_devd, E_devd, B_d, cap_devd, SHIFT_D, ch }; ch += nc(E_devd);

    partition_all_k<<<ch, 256, 0, stream>>>(pa);

    scatter_dev_k<12><<<256, 256, 0, stream>>>(x_tasks, ei_tdev, ei_tdev + E_tdev, E_tdev, aggT_dev);
    scatter_dev_k<5> <<<128, 256, 0, stream>>>(x_data,  ei_ddev, ei_ddev + E_ddev, E_ddev, aggD_dev);

    float* out_tasks = (float*)d_out;
    float* out_data  = out_tasks + (size_t)NT * 16;
    float* out_dev   = out_data  + (size_t)ND * 16;

    FinArgs fa;
    fa.p_dt = p_dt; fa.p_devt = p_devt; fa.p_to = p_to; fa.p_from = p_from;
    fa.p_td = p_td; fa.p_devd = p_devd;
    fa.c_dt = c_dt; fa.c_devt = c_devt; fa.c_to = c_to; fa.c_from = c_from;
    fa.c_td = c_td; fa.c_devd = c_devd;
    fa.cap_dt = cap_dt; fa.cap_devt = cap_devt; fa.cap_to = cap_to;
    fa.cap_from = cap_from; fa.cap_td = cap_td; fa.cap_devd = cap_devd;
    fa.x_tasks = x_tasks; fa.x_data = x_data; fa.x_dev = x_dev;
    fa.W_rel5 = W_rel5; fa.W_rel12 = W_rel12; fa.b_rel = b_rel;
    fa.W_root5 = W_root5; fa.W_root12 = W_root12; fa.ln_g = ln_g; fa.ln_b = ln_b;
    fa.out_tasks = out_tasks; fa.out_data = out_data;
    fa.NT = NT; fa.ND = ND; fa.Bt = B_t;

    agg_finalize_k<<<B_t + B_d, 256, 0, stream>>>(fa);

    finalize_dev_k<<<1, 64, 0, stream>>>(
        aggT_dev, aggD_dev, x_dev,
        W_rel12, W_rel5, b_rel, W_root12, ln_g, ln_b, out_dev, NDEV);
}

// Round 6
// 637.366 us; speedup vs baseline: 4.6185x; 1.0150x over previous
//
#include <hip/hip_runtime.h>
#include <hip/hip_fp16.h>

#define LRELU(v) ((v) >= 0.0f ? (v) : 0.01f * (v))
#define EPB 8192
#define SHIFT_T 7      // tasks bucket = 128 nodes
#define SHIFT_D 8      // data bucket = 256 nodes
#define MAXB 3200

// ===========================================================================
// Partition descriptor (6 node-destination relations)
// part entry = (src << shift) | (dst & mask)
// ===========================================================================
struct PartDesc {
    const int* src; const int* dst;
    unsigned int* part; int* cursor;
    int E, B, cap, shift, chunk0;
};

struct PrepArgs {
    PartDesc r[6];
    int part_end;
    // scatter_dev sections
    const int *tdev_e; int E_tdev; int sd12_b0, sd12_nb;
    const int *ddev_e; int E_ddev; int sd5_b0, sd5_nb;
    const float *x_tasks, *x_data, *x_dev;
    float *aggT_dev, *aggD_dev;
    // fp16 conversion sections
    __half *h_tasks; int NT; int ct_b0;
    __half *h_data;  int ND; int cd_b0;
};

// ---------------------------------------------------------------------------
template<int F>
__device__ __forceinline__ void loadrow(const float* __restrict__ x, unsigned s, float* v) {
    const float* p = x + (size_t)s * F;
    #pragma unroll
    for (int f = 0; f < F; ++f) v[f] = p[f];
}
template<>
__device__ __forceinline__ void loadrow<12>(const float* __restrict__ x, unsigned s, float* v) {
    const float4* p = (const float4*)(x + (size_t)s * 12);
    float4 a = p[0], b = p[1], c = p[2];
    v[0]=a.x; v[1]=a.y; v[2]=a.z; v[3]=a.w;
    v[4]=b.x; v[5]=b.y; v[6]=b.z; v[7]=b.w;
    v[8]=c.x; v[9]=c.y; v[10]=c.z; v[11]=c.w;
}

// dst=devices body: LDS accumulate directly (96 addrs, trivial volume)
template<int F>
__device__ void scatter_dev_body(const float* __restrict__ x, const int* __restrict__ src,
                                 const int* __restrict__ dst, int E,
                                 float* __restrict__ agg, float* s_agg,
                                 int bl, int nb, int t)
{
    for (int i = t; i < 8 * F; i += 256) s_agg[i] = 0.0f;
    __syncthreads();
    const int stride = nb * 256;
    for (int e = bl * 256 + t; e < E; e += stride) {
        float v[F];
        loadrow<F>(x, (unsigned)src[e], v);
        int d = dst[e];
        #pragma unroll
        for (int f = 0; f < F; ++f) atomicAdd(&s_agg[d * F + f], v[f]);
    }
    __syncthreads();
    if (t < 8 * F) atomicAdd(&agg[t], s_agg[t]);
}

// ===========================================================================
// prep_k: grid sections = [partition chunks][sd12][sd5][conv tasks][conv data]
// ===========================================================================
__global__ __launch_bounds__(256)
void prep_k(PrepArgs A)
{
    __shared__ int shmem[2 * MAXB];   // 25.6 KB
    const int bid = blockIdx.x;
    const int t = threadIdx.x;

    if (bid < A.part_end) {
        // ---------------- partition ----------------
        int* hist = shmem;
        int* base = shmem + MAXB;
        int ri = 0;
        #pragma unroll
        for (int k = 1; k < 6; ++k) if (bid >= A.r[k].chunk0) ri = k;
        const PartDesc d = A.r[ri];
        const int e0 = (bid - d.chunk0) * EPB;
        const int e1 = min(d.E, e0 + EPB);
        const int B = d.B, sh = d.shift;
        const unsigned mask = (1u << sh) - 1u;

        for (int i = t; i < B; i += 256) hist[i] = 0;
        __syncthreads();
        for (int e = e0 + t; e < e1; e += 256)
            atomicAdd(&hist[d.dst[e] >> sh], 1);
        __syncthreads();
        for (int i = t; i < B; i += 256) {
            int h = hist[i];
            base[i] = h ? atomicAdd(&d.cursor[i], h) : 0;
            hist[i] = 0;
        }
        __syncthreads();
        for (int e = e0 + t; e < e1; e += 256) {
            int dd = d.dst[e];
            int b = dd >> sh;
            int r = atomicAdd(&hist[b], 1) + base[b];
            if (r < d.cap)
                d.part[(size_t)b * d.cap + r] =
                    ((unsigned)d.src[e] << sh) | ((unsigned)dd & mask);
        }
    } else if (bid < A.sd5_b0) {
        // tasks -> devices: gather from x_tasks (BUGFIX: was x_dev)
        scatter_dev_body<12>(A.x_tasks, A.tdev_e, A.tdev_e + A.E_tdev, A.E_tdev,
                             A.aggT_dev, (float*)shmem, bid - A.sd12_b0, A.sd12_nb, t);
    } else if (bid < A.ct_b0) {
        // data -> devices: gather from x_data (BUGFIX: was x_dev)
        scatter_dev_body<5>(A.x_data, A.ddev_e, A.ddev_e + A.E_ddev, A.E_ddev,
                            A.aggD_dev, (float*)shmem, bid - A.sd5_b0, A.sd5_nb, t);
    } else if (bid < A.cd_b0) {
        // ---------------- conv tasks: fp32x12 -> fp16x16 (32B rows) ----------------
        int row = (bid - A.ct_b0) * 256 + t;
        if (row < A.NT) {
            const float* xr = A.x_tasks + (size_t)row * 12;
            __half h[16];
            #pragma unroll
            for (int j = 0; j < 12; ++j) h[j] = __float2half(xr[j]);
            #pragma unroll
            for (int j = 12; j < 16; ++j) h[j] = __half(0.0f);
            uint4* dst = (uint4*)(A.h_tasks + (size_t)row * 16);
            dst[0] = *(const uint4*)h;
            dst[1] = *(const uint4*)(h + 8);
        }
    } else {
        // ---------------- conv data: fp32x5 -> fp16x8 (16B rows) ----------------
        int row = (bid - A.cd_b0) * 256 + t;
        if (row < A.ND) {
            const float* xr = A.x_data + (size_t)row * 5;
            __half h[8];
            #pragma unroll
            for (int j = 0; j < 5; ++j) h[j] = __float2half(xr[j]);
            #pragma unroll
            for (int j = 5; j < 8; ++j) h[j] = __half(0.0f);
            *(uint4*)(A.h_data + (size_t)row * 8) = *(const uint4*)h;
        }
    }
}

// ===========================================================================
// Gather loaders for the agg phase
// ===========================================================================
struct LoadH8 {      // x_data fp16x8 rows: ONE dwordx4 request per edge
    const __half* x;
    __device__ __forceinline__ void operator()(unsigned s, float* v) const {
        uint4 u = *(const uint4*)(x + (size_t)s * 8);
        const __half2* h = (const __half2*)&u;
        float2 f0 = __half22float2(h[0]);
        float2 f1 = __half22float2(h[1]);
        float2 f2 = __half22float2(h[2]);
        v[0] = f0.x; v[1] = f0.y; v[2] = f1.x; v[3] = f1.y; v[4] = f2.x;
    }
};
struct LoadH16 {     // x_tasks fp16x16 rows: TWO dwordx4 requests per edge
    const __half* x;
    __device__ __forceinline__ void operator()(unsigned s, float* v) const {
        const uint4* p = (const uint4*)(x + (size_t)s * 16);
        uint4 u0 = p[0], u1 = p[1];
        const __half2* a = (const __half2*)&u0;
        const __half2* b = (const __half2*)&u1;
        float2 f;
        f = __half22float2(a[0]); v[0] = f.x; v[1] = f.y;
        f = __half22float2(a[1]); v[2] = f.x; v[3] = f.y;
        f = __half22float2(a[2]); v[4] = f.x; v[5] = f.y;
        f = __half22float2(a[3]); v[6] = f.x; v[7] = f.y;
        f = __half22float2(b[0]); v[8] = f.x; v[9] = f.y;
        f = __half22float2(b[1]); v[10] = f.x; v[11] = f.y;
    }
};
struct LoadF12 {     // x_dev fp32 (8 rows, L1-resident)
    const float* x;
    __device__ __forceinline__ void operator()(unsigned s, float* v) const {
        loadrow<12>(x, s, v);
    }
};

template<int F>
__device__ __forceinline__ void addrow(float* a, const float* v) {
    #pragma unroll
    for (int f = 0; f < F; ++f) atomicAdd(a + f, v[f]);      // ds_add_f32
}

// 4-wide unrolled edge loop: one uint4 part-load feeds 4 gathers in flight.
template<int F, int STRIDE, int BASE, int SHIFT, class LD>
__device__ __forceinline__
void agg_rel4(const unsigned* __restrict__ p, int cnt, LD ld, float* acc, int t)
{
    constexpr unsigned MASK = (1u << SHIFT) - 1u;
    int i = 4 * t;
    for (; i + 3 < cnt; i += 1024) {
        uint4 e = *(const uint4*)(p + i);
        float v0[F], v1[F], v2[F], v3[F];
        ld(e.x >> SHIFT, v0);
        ld(e.y >> SHIFT, v1);
        ld(e.z >> SHIFT, v2);
        ld(e.w >> SHIFT, v3);
        addrow<F>(acc + (e.x & MASK) * STRIDE + BASE, v0);
        addrow<F>(acc + (e.y & MASK) * STRIDE + BASE, v1);
        addrow<F>(acc + (e.z & MASK) * STRIDE + BASE, v2);
        addrow<F>(acc + (e.w & MASK) * STRIDE + BASE, v3);
    }
    const int jend = min(i + 4, cnt);
    for (int j = i; j < jend; ++j) {
        unsigned e = p[j];
        float v[F];
        ld(e >> SHIFT, v);
        addrow<F>(acc + (e & MASK) * STRIDE + BASE, v);
    }
}

// dot(f, sW[NFx16]) + bias -> LayerNorm -> leaky-relu -> store
template<int NF>
__device__ __forceinline__
void dot_ln_store(const float* __restrict__ f, const float* __restrict__ sW,
                  const float* __restrict__ sb, const float* __restrict__ sg,
                  const float* __restrict__ sbt, float* __restrict__ op)
{
    float o[16];
    #pragma unroll
    for (int k = 0; k < 16; ++k) o[k] = sb[k];
    const float4* w4 = (const float4*)sW;
    #pragma unroll
    for (int j = 0; j < NF; ++j) {
        const float fj = f[j];
        float4 w0 = w4[j*4+0], w1 = w4[j*4+1], w2 = w4[j*4+2], w3 = w4[j*4+3];
        o[0] =fmaf(fj,w0.x,o[0]);  o[1] =fmaf(fj,w0.y,o[1]);
        o[2] =fmaf(fj,w0.z,o[2]);  o[3] =fmaf(fj,w0.w,o[3]);
        o[4] =fmaf(fj,w1.x,o[4]);  o[5] =fmaf(fj,w1.y,o[5]);
        o[6] =fmaf(fj,w1.z,o[6]);  o[7] =fmaf(fj,w1.w,o[7]);
        o[8] =fmaf(fj,w2.x,o[8]);  o[9] =fmaf(fj,w2.y,o[9]);
        o[10]=fmaf(fj,w2.z,o[10]); o[11]=fmaf(fj,w2.w,o[11]);
        o[12]=fmaf(fj,w3.x,o[12]); o[13]=fmaf(fj,w3.y,o[13]);
        o[14]=fmaf(fj,w3.z,o[14]); o[15]=fmaf(fj,w3.w,o[15]);
    }
    float mu = 0.0f;
    #pragma unroll
    for (int k = 0; k < 16; ++k) mu += o[k];
    mu *= 0.0625f;
    float var = 0.0f;
    #pragma unroll
    for (int k = 0; k < 16; ++k) { float d = o[k] - mu; var = fmaf(d, d, var); }
    var *= 0.0625f;
    const float r = rsqrtf(var + 1e-5f);
    #pragma unroll
    for (int k = 0; k < 16; ++k) {
        float v = (o[k] - mu) * r * sg[k] + sbt[k];
        op[k] = LRELU(v);
    }
}

// ===========================================================================
// Fused aggregate + finalize
// ===========================================================================
struct FinArgs {
    const unsigned *p_dt, *p_devt, *p_to, *p_from, *p_td, *p_devd;
    const int *c_dt, *c_devt, *c_to, *c_from, *c_td, *c_devd;
    int cap_dt, cap_devt, cap_to, cap_from, cap_td, cap_devd;
    const float *x_tasks, *x_data, *x_dev;
    const __half *h_tasks, *h_data;
    const float *W_rel5, *W_rel12, *b_rel, *W_root5, *W_root12, *ln_g, *ln_b;
    float *out_tasks, *out_data;
    int NT, ND, Bt;
};

__global__ __launch_bounds__(256, 4)
void agg_finalize_k(FinArgs A)
{
    __shared__ __align__(16) float lds[6912];   // 27648 B
    const int t = threadIdx.x;

    if ((int)blockIdx.x < A.Bt) {
        // -------- tasks: f[53], acc 128 x stride 41 --------
        float* sW  = lds;
        float* sb  = lds + 848;
        float* sg  = lds + 864;
        float* sbt = lds + 880;
        float* acc = lds + 896;
        const int b  = blockIdx.x;
        const int n0 = b << SHIFT_T;
        const int nn = min(128, A.NT - n0);
        for (int i = t; i < 80; i += 256) sW[i] = A.W_rel5[i];
        for (int i = t; i < 192; i += 256) {
            sW[80  + i] = A.W_rel12[384 + i];
            sW[272 + i] = A.W_rel12[768 + i];
            sW[464 + i] = A.W_rel12[960 + i];
            sW[656 + i] = A.W_root12[i] + A.W_root12[384 + i]
                        + A.W_root12[768 + i] + A.W_root12[960 + i];
        }
        if (t < 16) {
            sb[t]  = A.b_rel[t] + A.b_rel[48 + t] + A.b_rel[96 + t] + A.b_rel[112 + t];
            sg[t]  = A.ln_g[t];
            sbt[t] = A.ln_b[t];
        }
        for (int i = t; i < 128 * 41; i += 256) acc[i] = 0.0f;
        __syncthreads();

        agg_rel4<5, 41, 0, SHIFT_T>(A.p_dt   + (size_t)b * A.cap_dt,   min(A.c_dt[b],   A.cap_dt),   LoadH8{A.h_data},   acc, t);
        agg_rel4<12,41, 5, SHIFT_T>(A.p_devt + (size_t)b * A.cap_devt, min(A.c_devt[b], A.cap_devt), LoadF12{A.x_dev},   acc, t);
        agg_rel4<12,41,17, SHIFT_T>(A.p_to   + (size_t)b * A.cap_to,   min(A.c_to[b],   A.cap_to),   LoadH16{A.h_tasks}, acc, t);
        agg_rel4<12,41,29, SHIFT_T>(A.p_from + (size_t)b * A.cap_from, min(A.c_from[b], A.cap_from), LoadH16{A.h_tasks}, acc, t);
        __syncthreads();

        if (t < nn) {
            float f[53];
            #pragma unroll
            for (int j = 0; j < 41; ++j) f[j] = acc[t * 41 + j];
            const float* xr = A.x_tasks + (size_t)(n0 + t) * 12;
            #pragma unroll
            for (int j = 0; j < 12; ++j) f[41 + j] = xr[j];
            dot_ln_store<53>(f, sW, sb, sg, sbt, A.out_tasks + (size_t)(n0 + t) * 16);
        }
    } else {
        // -------- data: f[29], acc 256 x stride 25 --------
        float* sW  = lds;
        float* sb  = lds + 464;
        float* sg  = lds + 480;
        float* sbt = lds + 496;
        float* acc = lds + 512;
        const int b  = blockIdx.x - A.Bt;
        const int n0 = b << SHIFT_D;
        const int nn = min(256, A.ND - n0);
        for (int i = t; i < 192; i += 256) {
            sW[i]       = A.W_rel12[i];
            sW[192 + i] = A.W_rel12[576 + i];
        }
        for (int i = t; i < 80; i += 256)
            sW[384 + i] = A.W_root5[i] + A.W_root5[80 + i];
        if (t < 16) {
            sb[t]  = A.b_rel[16 + t] + A.b_rel[80 + t];
            sg[t]  = A.ln_g[16 + t];
            sbt[t] = A.ln_b[16 + t];
        }
        for (int i = t; i < 256 * 25; i += 256) acc[i] = 0.0f;
        __syncthreads();

        agg_rel4<12,25, 0, SHIFT_D>(A.p_td   + (size_t)b * A.cap_td,   min(A.c_td[b],   A.cap_td),   LoadH16{A.h_tasks}, acc, t);
        agg_rel4<12,25,12, SHIFT_D>(A.p_devd + (size_t)b * A.cap_devd, min(A.c_devd[b], A.cap_devd), LoadF12{A.x_dev},   acc, t);
        __syncthreads();

        if (t < nn) {
            float f[29];
            #pragma unroll
            for (int j = 0; j < 24; ++j) f[j] = acc[t * 25 + j];
            const float* xr = A.x_data + (size_t)(n0 + t) * 5;
            #pragma unroll
            for (int j = 0; j < 5; ++j) f[24 + j] = xr[j];
            dot_ln_store<29>(f, sW, sb, sg, sbt, A.out_data + (size_t)(n0 + t) * 16);
        }
    }
}

// ===========================================================================
// Finalize devices (8 rows)
// ===========================================================================
__global__ void finalize_dev_k(const float* __restrict__ aggT, const float* __restrict__ aggD,
                               const float* __restrict__ x,
                               const float* __restrict__ W_rel12, const float* __restrict__ W_rel5,
                               const float* __restrict__ b_rel, const float* __restrict__ W_root12,
                               const float* __restrict__ ln_g, const float* __restrict__ ln_b,
                               float* __restrict__ out, int N)
{
    int i = threadIdx.x;
    if (i >= N) return;
    float acc[16];
    #pragma unroll
    for (int k = 0; k < 16; ++k) acc[k] = b_rel[32 + k] + b_rel[64 + k];
    #pragma unroll
    for (int j = 0; j < 12; ++j) {
        float fj = aggT[i * 12 + j];
        #pragma unroll
        for (int k = 0; k < 16; ++k) acc[k] = fmaf(fj, W_rel12[192 + j * 16 + k], acc[k]);
    }
    #pragma unroll
    for (int j = 0; j < 5; ++j) {
        float fj = aggD[i * 5 + j];
        #pragma unroll
        for (int k = 0; k < 16; ++k) acc[k] = fmaf(fj, W_rel5[80 + j * 16 + k], acc[k]);
    }
    #pragma unroll
    for (int j = 0; j < 12; ++j) {
        float fj = x[i * 12 + j];
        #pragma unroll
        for (int k = 0; k < 16; ++k)
            acc[k] = fmaf(fj, W_root12[192 + j * 16 + k] + W_root12[576 + j * 16 + k], acc[k]);
    }
    float mu = 0.0f;
    #pragma unroll
    for (int k = 0; k < 16; ++k) mu += acc[k];
    mu *= 0.0625f;
    float var = 0.0f;
    #pragma unroll
    for (int k = 0; k < 16; ++k) { float d = acc[k] - mu; var = fmaf(d, d, var); }
    var *= 0.0625f;
    const float r = rsqrtf(var + 1e-5f);
    #pragma unroll
    for (int k = 0; k < 16; ++k) {
        float v = (acc[k] - mu) * r * ln_g[32 + k] + ln_b[32 + k];
        out[i * 16 + k] = LRELU(v);
    }
}

// ===========================================================================
extern "C" void kernel_launch(void* const* d_in, const int* in_sizes, int n_in,
                              void* d_out, int out_size, void* d_ws, size_t ws_size,
                              hipStream_t stream)
{
    const float* x_tasks = (const float*)d_in[0];
    const float* x_data  = (const float*)d_in[1];
    const float* x_dev   = (const float*)d_in[2];
    const int* ei_dt    = (const int*)d_in[3];
    const int* ei_td    = (const int*)d_in[4];
    const int* ei_tdev  = (const int*)d_in[5];
    const int* ei_devt  = (const int*)d_in[6];
    const int* ei_ddev  = (const int*)d_in[7];
    const int* ei_devd  = (const int*)d_in[8];
    const int* ei_to    = (const int*)d_in[9];
    const int* ei_from  = (const int*)d_in[10];
    const float* W_rel5   = (const float*)d_in[11];
    const float* W_rel12  = (const float*)d_in[12];
    const float* b_rel    = (const float*)d_in[13];
    const float* W_root5  = (const float*)d_in[14];
    const float* W_root12 = (const float*)d_in[15];
    const float* ln_g     = (const float*)d_in[16];
    const float* ln_b     = (const float*)d_in[17];

    const int NT   = in_sizes[0] / 12;
    const int ND   = in_sizes[1] / 5;
    const int NDEV = in_sizes[2] / 12;
    const int E_dt   = in_sizes[3]  / 2;
    const int E_td   = in_sizes[4]  / 2;
    const int E_tdev = in_sizes[5]  / 2;
    const int E_devt = in_sizes[6]  / 2;
    const int E_ddev = in_sizes[7]  / 2;
    const int E_devd = in_sizes[8]  / 2;
    const int E_to   = in_sizes[9]  / 2;
    const int E_from = in_sizes[10] / 2;

    const int B_t = (NT + 127) / 128;    // 3125 task buckets (shift 7)
    const int B_d = (ND + 255) / 256;    // 782 data buckets (shift 8)

    auto capf = [](int E, int B) {       // mean + generous slack, x4 for uint4
        int mean = E / B + 1;
        int c = mean + 256 + mean / 8;
        return (c + 3) & ~3;
    };
    const int cap_dt   = capf(E_dt,   B_t);
    const int cap_devt = capf(E_devt, B_t);
    const int cap_to   = capf(E_to,   B_t);
    const int cap_from = capf(E_from, B_t);
    const int cap_td   = capf(E_td,   B_d);
    const int cap_devd = capf(E_devd, B_d);

    // ---- workspace ----
    float* ws = (float*)d_ws;
    size_t o = 0;
    int* c_dt   = (int*)(ws + o); o += MAXB;
    int* c_devt = (int*)(ws + o); o += MAXB;
    int* c_to   = (int*)(ws + o); o += MAXB;
    int* c_from = (int*)(ws + o); o += MAXB;
    int* c_td   = (int*)(ws + o); o += 800;
    int* c_devd = (int*)(ws + o); o += 800;
    float* aggT_dev = ws + o; o += 96;
    float* aggD_dev = ws + o; o += 48;
    const size_t zero_bytes = o * sizeof(float);
    o = (o + 3) & ~(size_t)3;                       // 16B-align
    __half* h_tasks = (__half*)(ws + o); o += (size_t)NT * 8;   // NT*16 halves
    __half* h_data  = (__half*)(ws + o); o += (size_t)ND * 4;   // ND*8 halves
    unsigned* p_dt   = (unsigned*)(ws + o); o += (size_t)B_t * cap_dt;
    unsigned* p_devt = (unsigned*)(ws + o); o += (size_t)B_t * cap_devt;
    unsigned* p_to   = (unsigned*)(ws + o); o += (size_t)B_t * cap_to;
    unsigned* p_from = (unsigned*)(ws + o); o += (size_t)B_t * cap_from;
    unsigned* p_td   = (unsigned*)(ws + o); o += (size_t)B_d * cap_td;
    unsigned* p_devd = (unsigned*)(ws + o); o += (size_t)B_d * cap_devd;

    hipMemsetAsync(d_ws, 0, zero_bytes, stream);

    auto nc = [](int e) { return (e + EPB - 1) / EPB; };
    PrepArgs pa;
    int ch = 0;
    pa.r[0] = { ei_dt,   ei_dt   + E_dt,   p_dt,   c_dt,   E_dt,   B_t, cap_dt,   SHIFT_T, ch }; ch += nc(E_dt);
    pa.r[1] = { ei_devt, ei_devt + E_devt, p_devt, c_devt, E_devt, B_t, cap_devt, SHIFT_T, ch }; ch += nc(E_devt);
    pa.r[2] = { ei_to,   ei_to   + E_to,   p_to,   c_to,   E_to,   B_t, cap_to,   SHIFT_T, ch }; ch += nc(E_to);
    pa.r[3] = { ei_from, ei_from + E_from, p_from, c_from, E_from, B_t, cap_from, SHIFT_T, ch }; ch += nc(E_from);
    pa.r[4] = { ei_td,   ei_td   + E_td,   p_td,   c_td,   E_td,   B_d, cap_td,   SHIFT_D, ch }; ch += nc(E_td);
    pa.r[5] = { ei_devd, ei_devd + E_devd, p_devd, c_devd, E_devd, B_d, cap_devd, SHIFT_D, ch }; ch += nc(E_devd);
    pa.part_end = ch;
    pa.tdev_e = ei_tdev; pa.E_tdev = E_tdev; pa.sd12_b0 = ch; pa.sd12_nb = 192; ch += 192;
    pa.ddev_e = ei_ddev; pa.E_ddev = E_ddev; pa.sd5_b0  = ch; pa.sd5_nb  = 96;  ch += 96;
    pa.x_tasks = x_tasks; pa.x_data = x_data; pa.x_dev = x_dev;
    pa.aggT_dev = aggT_dev; pa.aggD_dev = aggD_dev;
    pa.h_tasks = h_tasks; pa.NT = NT; pa.ct_b0 = ch; ch += (NT + 255) / 256;
    pa.h_data  = h_data;  pa.ND = ND; pa.cd_b0 = ch; ch += (ND + 255) / 256;

    prep_k<<<ch, 256, 0, stream>>>(pa);

    float* out_tasks = (float*)d_out;
    float* out_data  = out_tasks + (size_t)NT * 16;
    float* out_dev   = out_data  + (size_t)ND * 16;

    FinArgs fa;
    fa.p_dt = p_dt; fa.p_devt = p_devt; fa.p_to = p_to; fa.p_from = p_from;
    fa.p_td = p_td; fa.p_devd = p_devd;
    fa.c_dt = c_dt; fa.c_devt = c_devt; fa.c_to = c_to; fa.c_from = c_from;
    fa.c_td = c_td; fa.c_devd = c_devd;
    fa.cap_dt = cap_dt; fa.cap_devt = cap_devt; fa.cap_to = cap_to;
    fa.cap_from = cap_from; fa.cap_td = cap_td; fa.cap_devd = cap_devd;
    fa.x_tasks = x_tasks; fa.x_data = x_data; fa.x_dev = x_dev;
    fa.h_tasks = h_tasks; fa.h_data = h_data;
    fa.W_rel5 = W_rel5; fa.W_rel12 = W_rel12; fa.b_rel = b_rel;
    fa.W_root5 = W_root5; fa.W_root12 = W_root12; fa.ln_g = ln_g; fa.ln_b = ln_b;
    fa.out_tasks = out_tasks; fa.out_data = out_data;
    fa.NT = NT; fa.ND = ND; fa.Bt = B_t;

    agg_finalize_k<<<B_t + B_d, 256, 0, stream>>>(fa);

    finalize_dev_k<<<1, 64, 0, stream>>>(
        aggT_dev, aggD_dev, x_dev,
        W_rel12, W_rel5, b_rel, W_root12, ln_g, ln_b, out_dev, NDEV);
}

// Round 7
// 632.491 us; speedup vs baseline: 4.6541x; 1.0077x over previous
//
#include <hip/hip_runtime.h>
#include <hip/hip_fp16.h>

#define LRELU(v) ((v) >= 0.0f ? (v) : 0.01f * (v))
#define EPB 8192
#define SHIFT 7          // 128 nodes per bucket (all relations)
#define PAIRS 1600       // packed u16 histogram pairs (covers B <= 3200)

// ===========================================================================
// prep_k: [partition x6][scatter-dev x2][fp16 conversion x2]
// part entry = (src << 7) | (dst & 127)
// ===========================================================================
struct PartDesc {
    const int* src; const int* dst;
    unsigned* part; int* cursor;
    int E, B, cap, chunk0;
};

struct PrepArgs {
    PartDesc r[6];
    int part_end;
    const int *tdev_e; int E_tdev; int sd12_b0, sd12_nb;
    const int *ddev_e; int E_ddev; int sd5_b0, sd5_nb;
    const float *x_tasks, *x_data, *x_dev;
    float *aggT_dev, *aggD_dev;
    __half *h_tasks; int NT; int ct_b0;
    __half *h_data;  int ND; int cd_b0;
};

template<int F>
__device__ __forceinline__ void loadrow(const float* __restrict__ x, unsigned s, float* v) {
    const float* p = x + (size_t)s * F;
    #pragma unroll
    for (int f = 0; f < F; ++f) v[f] = p[f];
}
template<>
__device__ __forceinline__ void loadrow<12>(const float* __restrict__ x, unsigned s, float* v) {
    const float4* p = (const float4*)(x + (size_t)s * 12);
    float4 a = p[0], b = p[1], c = p[2];
    v[0]=a.x; v[1]=a.y; v[2]=a.z; v[3]=a.w;
    v[4]=b.x; v[5]=b.y; v[6]=b.z; v[7]=b.w;
    v[8]=c.x; v[9]=c.y; v[10]=c.z; v[11]=c.w;
}

template<int F>
__device__ void scatter_dev_body(const float* __restrict__ x, const int* __restrict__ src,
                                 const int* __restrict__ dst, int E,
                                 float* __restrict__ agg, float* s_agg,
                                 int bl, int nb, int t)
{
    for (int i = t; i < 8 * F; i += 256) s_agg[i] = 0.0f;
    __syncthreads();
    const int stride = nb * 256;
    for (int e = bl * 256 + t; e < E; e += stride) {
        float v[F];
        loadrow<F>(x, (unsigned)src[e], v);
        int d = dst[e];
        #pragma unroll
        for (int f = 0; f < F; ++f) atomicAdd(&s_agg[d * F + f], v[f]);
    }
    __syncthreads();
    if (t < 8 * F) atomicAdd(&agg[t], s_agg[t]);
}

__global__ __launch_bounds__(256)
void prep_k(PrepArgs A)
{
    __shared__ unsigned shp[2 * PAIRS];   // 12.8 KB
    const int bid = blockIdx.x;
    const int t = threadIdx.x;

    if (bid < A.part_end) {
        unsigned* hist = shp;
        unsigned* base = shp + PAIRS;
        int ri = 0;
        #pragma unroll
        for (int k = 1; k < 6; ++k) if (bid >= A.r[k].chunk0) ri = k;
        const PartDesc d = A.r[ri];
        const int e0 = (bid - d.chunk0) * EPB;
        const int e1 = min(d.E, e0 + EPB);
        const int npair = (d.B + 1) >> 1;

        for (int i = t; i < npair; i += 256) hist[i] = 0u;
        __syncthreads();
        for (int e = e0 + t; e < e1; e += 256) {
            int b = d.dst[e] >> SHIFT;
            atomicAdd(&hist[b >> 1], 1u << ((b & 1) << 4));
        }
        __syncthreads();
        for (int i = t; i < npair; i += 256) {
            unsigned h = hist[i];
            unsigned lo = h & 0xffffu, hi = h >> 16;
            unsigned blo = lo ? (unsigned)atomicAdd(&d.cursor[2 * i],     (int)lo) : 0u;
            unsigned bhi = hi ? (unsigned)atomicAdd(&d.cursor[2 * i + 1], (int)hi) : 0u;
            base[i] = (blo & 0xffffu) | (bhi << 16);
            hist[i] = 0u;
        }
        __syncthreads();
        for (int e = e0 + t; e < e1; e += 256) {
            int dd = d.dst[e];
            int b = dd >> SHIFT;
            unsigned s16 = (unsigned)(b & 1) << 4;
            unsigned r = atomicAdd(&hist[b >> 1], 1u << s16);
            unsigned idx = ((r >> s16) & 0xffffu) + ((base[b >> 1] >> s16) & 0xffffu);
            if ((int)idx < d.cap)
                d.part[(size_t)b * d.cap + idx] =
                    ((unsigned)d.src[e] << SHIFT) | ((unsigned)dd & 127u);
        }
    } else if (bid < A.sd5_b0) {
        scatter_dev_body<12>(A.x_tasks, A.tdev_e, A.tdev_e + A.E_tdev, A.E_tdev,
                             A.aggT_dev, (float*)shp, bid - A.sd12_b0, A.sd12_nb, t);
    } else if (bid < A.ct_b0) {
        scatter_dev_body<5>(A.x_data, A.ddev_e, A.ddev_e + A.E_ddev, A.E_ddev,
                            A.aggD_dev, (float*)shp, bid - A.sd5_b0, A.sd5_nb, t);
    } else if (bid < A.cd_b0) {
        int row = (bid - A.ct_b0) * 256 + t;
        if (row < A.NT) {
            const float* xr = A.x_tasks + (size_t)row * 12;
            __half h[16];
            #pragma unroll
            for (int j = 0; j < 12; ++j) h[j] = __float2half(xr[j]);
            #pragma unroll
            for (int j = 12; j < 16; ++j) h[j] = __half(0.0f);
            uint4* dst = (uint4*)(A.h_tasks + (size_t)row * 16);
            dst[0] = *(const uint4*)h;
            dst[1] = *(const uint4*)(h + 8);
        }
    } else {
        int row = (bid - A.cd_b0) * 256 + t;
        if (row < A.ND) {
            const float* xr = A.x_data + (size_t)row * 5;
            __half h[8];
            #pragma unroll
            for (int j = 0; j < 5; ++j) h[j] = __float2half(xr[j]);
            #pragma unroll
            for (int j = 5; j < 8; ++j) h[j] = __half(0.0f);
            *(uint4*)(A.h_data + (size_t)row * 8) = *(const uint4*)h;
        }
    }
}

// ===========================================================================
// agg_k: one block per (relation, bucket). LDS acc = 128 x F (<= 6 KB).
// ===========================================================================
struct LoadH8 {
    const __half* x;
    __device__ __forceinline__ void operator()(unsigned s, float* v) const {
        uint4 u = *(const uint4*)(x + (size_t)s * 8);
        const __half2* h = (const __half2*)&u;
        float2 f0 = __half22float2(h[0]);
        float2 f1 = __half22float2(h[1]);
        float2 f2 = __half22float2(h[2]);
        v[0] = f0.x; v[1] = f0.y; v[2] = f1.x; v[3] = f1.y; v[4] = f2.x;
    }
};
struct LoadH16 {
    const __half* x;
    __device__ __forceinline__ void operator()(unsigned s, float* v) const {
        const uint4* p = (const uint4*)(x + (size_t)s * 16);
        uint4 u0 = p[0], u1 = p[1];
        const __half2* a = (const __half2*)&u0;
        const __half2* b = (const __half2*)&u1;
        float2 f;
        f = __half22float2(a[0]); v[0] = f.x; v[1] = f.y;
        f = __half22float2(a[1]); v[2] = f.x; v[3] = f.y;
        f = __half22float2(a[2]); v[4] = f.x; v[5] = f.y;
        f = __half22float2(a[3]); v[6] = f.x; v[7] = f.y;
        f = __half22float2(b[0]); v[8] = f.x; v[9] = f.y;
        f = __half22float2(b[1]); v[10] = f.x; v[11] = f.y;
    }
};
struct LoadF12 {
    const float* x;
    __device__ __forceinline__ void operator()(unsigned s, float* v) const {
        loadrow<12>(x, s, v);
    }
};

template<int F>
__device__ __forceinline__ void addrow(float* a, const float* v) {
    #pragma unroll
    for (int f = 0; f < F; ++f) atomicAdd(a + f, v[f]);      // ds_add_f32
}

template<int F, class LD>
__device__ __forceinline__
void agg_rel4(const unsigned* __restrict__ p, int cnt, LD ld, float* acc, int t)
{
    int i = 4 * t;
    for (; i + 3 < cnt; i += 1024) {
        uint4 e = *(const uint4*)(p + i);
        float v0[F], v1[F], v2[F], v3[F];
        ld(e.x >> SHIFT, v0);
        ld(e.y >> SHIFT, v1);
        ld(e.z >> SHIFT, v2);
        ld(e.w >> SHIFT, v3);
        addrow<F>(acc + (e.x & 127u) * F, v0);
        addrow<F>(acc + (e.y & 127u) * F, v1);
        addrow<F>(acc + (e.z & 127u) * F, v2);
        addrow<F>(acc + (e.w & 127u) * F, v3);
    }
    const int jend = min(i + 4, cnt);
    for (int j = i; j < jend; ++j) {
        unsigned e = p[j];
        float v[F];
        ld(e >> SHIFT, v);
        addrow<F>(acc + (e & 127u) * F, v);
    }
}

struct AggDesc { const unsigned* part; const int* cursor; int cap, b0; };
struct AggArgs {
    AggDesc r[6];
    const __half *h_tasks, *h_data; const float* x_dev;
    __half *aD_t, *aDev_t, *aTo, *aFrom, *aT_d, *aDev_d;
    int NT, ND;
};

template<int F, int OSTR, class LD>
__device__ __forceinline__
void agg_body(const unsigned* p, int cnt, LD ld, float* acc,
              __half* out, int N, int n0, int t)
{
    const int nn = min(128, N - n0);
    for (int i = t; i < 128 * F; i += 256) acc[i] = 0.0f;
    __syncthreads();
    agg_rel4<F>(p, cnt, ld, acc, t);
    __syncthreads();
    __half* o = out + (size_t)n0 * OSTR;
    for (int i = t; i < nn * OSTR; i += 256) {
        int n = i / OSTR, c = i - n * OSTR;
        float v = (c < F) ? acc[n * F + c] : 0.0f;
        o[i] = __float2half(v);
    }
}

__global__ __launch_bounds__(256, 6)
void agg_k(AggArgs A)
{
    __shared__ float acc[128 * 12];   // 6 KB
    const int bid = blockIdx.x;
    const int t = threadIdx.x;
    int ri = 0;
    #pragma unroll
    for (int k = 1; k < 6; ++k) if (bid >= A.r[k].b0) ri = k;
    const AggDesc d = A.r[ri];
    const int b = bid - d.b0;
    const unsigned* p = d.part + (size_t)b * d.cap;
    const int cnt = min(d.cursor[b], d.cap);
    const int n0 = b << SHIFT;

    if (ri == 0)      agg_body<5, 6 >(p, cnt, LoadH8 {A.h_data},  acc, A.aD_t,   A.NT, n0, t);
    else if (ri == 1) agg_body<12, 12>(p, cnt, LoadF12{A.x_dev},   acc, A.aDev_t, A.NT, n0, t);
    else if (ri == 2) agg_body<12, 12>(p, cnt, LoadH16{A.h_tasks}, acc, A.aTo,    A.NT, n0, t);
    else if (ri == 3) agg_body<12, 12>(p, cnt, LoadH16{A.h_tasks}, acc, A.aFrom,  A.NT, n0, t);
    else if (ri == 4) agg_body<12, 12>(p, cnt, LoadH16{A.h_tasks}, acc, A.aT_d,   A.ND, n0, t);
    else              agg_body<12, 12>(p, cnt, LoadF12{A.x_dev},   acc, A.aDev_d, A.ND, n0, t);
}

// ===========================================================================
// finalize_k: coalesced read of agg arrays -> dot + LN + leaky-relu -> out
// ===========================================================================
__device__ __forceinline__ float2 upk(unsigned u) {
    __half2 h = *(__half2*)&u; return __half22float2(h);
}
__device__ __forceinline__ void load12h(const __half* base, size_t i, float* f) {
    const uint2* q = (const uint2*)(base + i * 12);   // 24B rows, 8B aligned
    uint2 u0 = q[0], u1 = q[1], u2 = q[2];
    float2 x;
    x = upk(u0.x); f[0]  = x.x; f[1]  = x.y;
    x = upk(u0.y); f[2]  = x.x; f[3]  = x.y;
    x = upk(u1.x); f[4]  = x.x; f[5]  = x.y;
    x = upk(u1.y); f[6]  = x.x; f[7]  = x.y;
    x = upk(u2.x); f[8]  = x.x; f[9]  = x.y;
    x = upk(u2.y); f[10] = x.x; f[11] = x.y;
}

template<int NF>
__device__ __forceinline__
void dot_ln_store(const float* __restrict__ f, const float* __restrict__ sW,
                  const float* __restrict__ sb, const float* __restrict__ sg,
                  const float* __restrict__ sbt, float* __restrict__ op)
{
    float o[16];
    #pragma unroll
    for (int k = 0; k < 16; ++k) o[k] = sb[k];
    const float4* w4 = (const float4*)sW;
    #pragma unroll
    for (int j = 0; j < NF; ++j) {
        const float fj = f[j];
        float4 w0 = w4[j*4+0], w1 = w4[j*4+1], w2 = w4[j*4+2], w3 = w4[j*4+3];
        o[0] =fmaf(fj,w0.x,o[0]);  o[1] =fmaf(fj,w0.y,o[1]);
        o[2] =fmaf(fj,w0.z,o[2]);  o[3] =fmaf(fj,w0.w,o[3]);
        o[4] =fmaf(fj,w1.x,o[4]);  o[5] =fmaf(fj,w1.y,o[5]);
        o[6] =fmaf(fj,w1.z,o[6]);  o[7] =fmaf(fj,w1.w,o[7]);
        o[8] =fmaf(fj,w2.x,o[8]);  o[9] =fmaf(fj,w2.y,o[9]);
        o[10]=fmaf(fj,w2.z,o[10]); o[11]=fmaf(fj,w2.w,o[11]);
        o[12]=fmaf(fj,w3.x,o[12]); o[13]=fmaf(fj,w3.y,o[13]);
        o[14]=fmaf(fj,w3.z,o[14]); o[15]=fmaf(fj,w3.w,o[15]);
    }
    float mu = 0.0f;
    #pragma unroll
    for (int k = 0; k < 16; ++k) mu += o[k];
    mu *= 0.0625f;
    float var = 0.0f;
    #pragma unroll
    for (int k = 0; k < 16; ++k) { float d = o[k] - mu; var = fmaf(d, d, var); }
    var *= 0.0625f;
    const float r = rsqrtf(var + 1e-5f);
    #pragma unroll
    for (int k = 0; k < 16; ++k) {
        float v = (o[k] - mu) * r * sg[k] + sbt[k];
        op[k] = LRELU(v);
    }
}

struct FinArgs {
    const __half *aD_t, *aDev_t, *aTo, *aFrom, *aT_d, *aDev_d;
    const float *x_tasks, *x_data, *x_dev;
    const float *aggT_dev, *aggD_dev;
    const float *W_rel5, *W_rel12, *b_rel, *W_root5, *W_root12, *ln_g, *ln_b;
    float *out_tasks, *out_data, *out_dev;
    int NT, ND, NDEV, Bt, Bd;
};

__global__ __launch_bounds__(256, 4)
void finalize_k(FinArgs A)
{
    __shared__ __align__(16) float lds[896];
    const int bid = blockIdx.x;
    const int t = threadIdx.x;

    if (bid < A.Bt) {
        float* sW = lds; float* sb = lds + 848; float* sg = lds + 864; float* sbt = lds + 880;
        for (int i = t; i < 80; i += 256) sW[i] = A.W_rel5[i];            // W_rel5[0]
        for (int i = t; i < 192; i += 256) {
            sW[80  + i] = A.W_rel12[384 + i];                             // W_rel12[2]
            sW[272 + i] = A.W_rel12[768 + i];                             // W_rel12[4]
            sW[464 + i] = A.W_rel12[960 + i];                             // W_rel12[5]
            sW[656 + i] = A.W_root12[i] + A.W_root12[384 + i]
                        + A.W_root12[768 + i] + A.W_root12[960 + i];
        }
        if (t < 16) {
            sb[t]  = A.b_rel[t] + A.b_rel[48 + t] + A.b_rel[96 + t] + A.b_rel[112 + t];
            sg[t]  = A.ln_g[t];
            sbt[t] = A.ln_b[t];
        }
        __syncthreads();
        const int i = bid * 256 + t;
        if (i < A.NT) {
            float f[53];
            {
                const unsigned* q = (const unsigned*)A.aD_t + (size_t)i * 3;  // 12B rows
                unsigned u0 = q[0], u1 = q[1], u2 = q[2];
                float2 a = upk(u0), b = upk(u1), c = upk(u2);
                f[0] = a.x; f[1] = a.y; f[2] = b.x; f[3] = b.y; f[4] = c.x;
            }
            load12h(A.aDev_t, i, f + 5);
            load12h(A.aTo,   i, f + 17);
            load12h(A.aFrom, i, f + 29);
            const float4* xr = (const float4*)(A.x_tasks + (size_t)i * 12);
            float4 x0 = xr[0], x1 = xr[1], x2 = xr[2];
            f[41]=x0.x; f[42]=x0.y; f[43]=x0.z; f[44]=x0.w;
            f[45]=x1.x; f[46]=x1.y; f[47]=x1.z; f[48]=x1.w;
            f[49]=x2.x; f[50]=x2.y; f[51]=x2.z; f[52]=x2.w;
            dot_ln_store<53>(f, sW, sb, sg, sbt, A.out_tasks + (size_t)i * 16);
        }
    } else if (bid < A.Bt + A.Bd) {
        float* sW = lds; float* sb = lds + 464; float* sg = lds + 480; float* sbt = lds + 496;
        for (int i = t; i < 192; i += 256) {
            sW[i]       = A.W_rel12[i];                                   // W_rel12[0]
            sW[192 + i] = A.W_rel12[576 + i];                             // W_rel12[3]
        }
        for (int i = t; i < 80; i += 256)
            sW[384 + i] = A.W_root5[i] + A.W_root5[80 + i];
        if (t < 16) {
            sb[t]  = A.b_rel[16 + t] + A.b_rel[80 + t];
            sg[t]  = A.ln_g[16 + t];
            sbt[t] = A.ln_b[16 + t];
        }
        __syncthreads();
        const int i = (bid - A.Bt) * 256 + t;
        if (i < A.ND) {
            float f[29];
            load12h(A.aT_d,   i, f);
            load12h(A.aDev_d, i, f + 12);
            const float* xr = A.x_data + (size_t)i * 5;
            #pragma unroll
            for (int j = 0; j < 5; ++j) f[24 + j] = xr[j];
            dot_ln_store<29>(f, sW, sb, sg, sbt, A.out_data + (size_t)i * 16);
        }
    } else {
        const int i = t;
        if (i < A.NDEV) {
            float acc[16];
            #pragma unroll
            for (int k = 0; k < 16; ++k) acc[k] = A.b_rel[32 + k] + A.b_rel[64 + k];
            #pragma unroll
            for (int j = 0; j < 12; ++j) {
                float fj = A.aggT_dev[i * 12 + j];
                #pragma unroll
                for (int k = 0; k < 16; ++k) acc[k] = fmaf(fj, A.W_rel12[192 + j * 16 + k], acc[k]);
            }
            #pragma unroll
            for (int j = 0; j < 5; ++j) {
                float fj = A.aggD_dev[i * 5 + j];
                #pragma unroll
                for (int k = 0; k < 16; ++k) acc[k] = fmaf(fj, A.W_rel5[80 + j * 16 + k], acc[k]);
            }
            #pragma unroll
            for (int j = 0; j < 12; ++j) {
                float fj = A.x_dev[i * 12 + j];
                #pragma unroll
                for (int k = 0; k < 16; ++k)
                    acc[k] = fmaf(fj, A.W_root12[192 + j * 16 + k] + A.W_root12[576 + j * 16 + k], acc[k]);
            }
            float mu = 0.0f;
            #pragma unroll
            for (int k = 0; k < 16; ++k) mu += acc[k];
            mu *= 0.0625f;
            float var = 0.0f;
            #pragma unroll
            for (int k = 0; k < 16; ++k) { float d = acc[k] - mu; var = fmaf(d, d, var); }
            var *= 0.0625f;
            const float r = rsqrtf(var + 1e-5f);
            #pragma unroll
            for (int k = 0; k < 16; ++k) {
                float v = (acc[k] - mu) * r * A.ln_g[32 + k] + A.ln_b[32 + k];
                A.out_dev[i * 16 + k] = LRELU(v);
            }
        }
    }
}

// ===========================================================================
extern "C" void kernel_launch(void* const* d_in, const int* in_sizes, int n_in,
                              void* d_out, int out_size, void* d_ws, size_t ws_size,
                              hipStream_t stream)
{
    const float* x_tasks = (const float*)d_in[0];
    const float* x_data  = (const float*)d_in[1];
    const float* x_dev   = (const float*)d_in[2];
    const int* ei_dt    = (const int*)d_in[3];
    const int* ei_td    = (const int*)d_in[4];
    const int* ei_tdev  = (const int*)d_in[5];
    const int* ei_devt  = (const int*)d_in[6];
    const int* ei_ddev  = (const int*)d_in[7];
    const int* ei_devd  = (const int*)d_in[8];
    const int* ei_to    = (const int*)d_in[9];
    const int* ei_from  = (const int*)d_in[10];
    const float* W_rel5   = (const float*)d_in[11];
    const float* W_rel12  = (const float*)d_in[12];
    const float* b_rel    = (const float*)d_in[13];
    const float* W_root5  = (const float*)d_in[14];
    const float* W_root12 = (const float*)d_in[15];
    const float* ln_g     = (const float*)d_in[16];
    const float* ln_b     = (const float*)d_in[17];

    const int NT   = in_sizes[0] / 12;
    const int ND   = in_sizes[1] / 5;
    const int NDEV = in_sizes[2] / 12;
    const int E_dt   = in_sizes[3]  / 2;
    const int E_td   = in_sizes[4]  / 2;
    const int E_tdev = in_sizes[5]  / 2;
    const int E_devt = in_sizes[6]  / 2;
    const int E_ddev = in_sizes[7]  / 2;
    const int E_devd = in_sizes[8]  / 2;
    const int E_to   = in_sizes[9]  / 2;
    const int E_from = in_sizes[10] / 2;

    const int B_t = (NT + 127) / 128;   // 3125
    const int B_d = (ND + 127) / 128;   // 1563

    auto capf = [](int E, int B) {      // mean + >=10 sigma slack, x4-rounded
        int mean = E / B + 1;
        int c = mean + mean / 4 + 128;
        return (c + 3) & ~3;
    };
    const int cap_dt   = capf(E_dt,   B_t);
    const int cap_devt = capf(E_devt, B_t);
    const int cap_to   = capf(E_to,   B_t);
    const int cap_from = capf(E_from, B_t);
    const int cap_td   = capf(E_td,   B_d);
    const int cap_devd = capf(E_devd, B_d);

    // ---- workspace (~94 MB) ----
    float* ws = (float*)d_ws;
    size_t o = 0;
    int* c_dt   = (int*)(ws + o); o += 3200;
    int* c_devt = (int*)(ws + o); o += 3200;
    int* c_to   = (int*)(ws + o); o += 3200;
    int* c_from = (int*)(ws + o); o += 3200;
    int* c_td   = (int*)(ws + o); o += 1600;
    int* c_devd = (int*)(ws + o); o += 1600;
    float* aggT_dev = ws + o; o += 96;
    float* aggD_dev = ws + o; o += 48;
    const size_t zero_bytes = o * sizeof(float);
    o = (o + 3) & ~(size_t)3;
    __half* h_tasks = (__half*)(ws + o); o += (size_t)NT * 8;  // 16 halves/row
    __half* h_data  = (__half*)(ws + o); o += (size_t)ND * 4;  // 8 halves/row
    __half* aD_t    = (__half*)(ws + o); o += (size_t)NT * 3;  // stride 6 halves
    __half* aDev_t  = (__half*)(ws + o); o += (size_t)NT * 6;  // stride 12 halves
    __half* aTo     = (__half*)(ws + o); o += (size_t)NT * 6;
    __half* aFrom   = (__half*)(ws + o); o += (size_t)NT * 6;
    __half* aT_d    = (__half*)(ws + o); o += (size_t)ND * 6;
    __half* aDev_d  = (__half*)(ws + o); o += (size_t)ND * 6;
    unsigned* p_dt   = (unsigned*)(ws + o); o += (size_t)B_t * cap_dt;
    unsigned* p_devt = (unsigned*)(ws + o); o += (size_t)B_t * cap_devt;
    unsigned* p_to   = (unsigned*)(ws + o); o += (size_t)B_t * cap_to;
    unsigned* p_from = (unsigned*)(ws + o); o += (size_t)B_t * cap_from;
    unsigned* p_td   = (unsigned*)(ws + o); o += (size_t)B_d * cap_td;
    unsigned* p_devd = (unsigned*)(ws + o); o += (size_t)B_d * cap_devd;

    hipMemsetAsync(d_ws, 0, zero_bytes, stream);

    auto nc = [](int e) { return (e + EPB - 1) / EPB; };
    PrepArgs pa;
    int ch = 0;
    pa.r[0] = { ei_dt,   ei_dt   + E_dt,   p_dt,   c_dt,   E_dt,   B_t, cap_dt,   ch }; ch += nc(E_dt);
    pa.r[1] = { ei_devt, ei_devt + E_devt, p_devt, c_devt, E_devt, B_t, cap_devt, ch }; ch += nc(E_devt);
    pa.r[2] = { ei_to,   ei_to   + E_to,   p_to,   c_to,   E_to,   B_t, cap_to,   ch }; ch += nc(E_to);
    pa.r[3] = { ei_from, ei_from + E_from, p_from, c_from, E_from, B_t, cap_from, ch }; ch += nc(E_from);
    pa.r[4] = { ei_td,   ei_td   + E_td,   p_td,   c_td,   E_td,   B_d, cap_td,   ch }; ch += nc(E_td);
    pa.r[5] = { ei_devd, ei_devd + E_devd, p_devd, c_devd, E_devd, B_d, cap_devd, ch }; ch += nc(E_devd);
    pa.part_end = ch;
    pa.tdev_e = ei_tdev; pa.E_tdev = E_tdev; pa.sd12_b0 = ch; pa.sd12_nb = 192; ch += 192;
    pa.ddev_e = ei_ddev; pa.E_ddev = E_ddev; pa.sd5_b0  = ch; pa.sd5_nb  = 96;  ch += 96;
    pa.x_tasks = x_tasks; pa.x_data = x_data; pa.x_dev = x_dev;
    pa.aggT_dev = aggT_dev; pa.aggD_dev = aggD_dev;
    pa.h_tasks = h_tasks; pa.NT = NT; pa.ct_b0 = ch; ch += (NT + 255) / 256;
    pa.h_data  = h_data;  pa.ND = ND; pa.cd_b0 = ch; ch += (ND + 255) / 256;

    prep_k<<<ch, 256, 0, stream>>>(pa);

    AggArgs aa;
    int ab = 0;
    aa.r[0] = { p_dt,   c_dt,   cap_dt,   ab }; ab += B_t;
    aa.r[1] = { p_devt, c_devt, cap_devt, ab }; ab += B_t;
    aa.r[2] = { p_to,   c_to,   cap_to,   ab }; ab += B_t;
    aa.r[3] = { p_from, c_from, cap_from, ab }; ab += B_t;
    aa.r[4] = { p_td,   c_td,   cap_td,   ab }; ab += B_d;
    aa.r[5] = { p_devd, c_devd, cap_devd, ab }; ab += B_d;
    aa.h_tasks = h_tasks; aa.h_data = h_data; aa.x_dev = x_dev;
    aa.aD_t = aD_t; aa.aDev_t = aDev_t; aa.aTo = aTo; aa.aFrom = aFrom;
    aa.aT_d = aT_d; aa.aDev_d = aDev_d;
    aa.NT = NT; aa.ND = ND;

    agg_k<<<ab, 256, 0, stream>>>(aa);

    float* out_tasks = (float*)d_out;
    float* out_data  = out_tasks + (size_t)NT * 16;
    float* out_dev   = out_data  + (size_t)ND * 16;

    FinArgs fa;
    fa.aD_t = aD_t; fa.aDev_t = aDev_t; fa.aTo = aTo; fa.aFrom = aFrom;
    fa.aT_d = aT_d; fa.aDev_d = aDev_d;
    fa.x_tasks = x_tasks; fa.x_data = x_data; fa.x_dev = x_dev;
    fa.aggT_dev = aggT_dev; fa.aggD_dev = aggD_dev;
    fa.W_rel5 = W_rel5; fa.W_rel12 = W_rel12; fa.b_rel = b_rel;
    fa.W_root5 = W_root5; fa.W_root12 = W_root12; fa.ln_g = ln_g; fa.ln_b = ln_b;
    fa.out_tasks = out_tasks; fa.out_data = out_data; fa.out_dev = out_dev;
    fa.NT = NT; fa.ND = ND; fa.NDEV = NDEV;
    fa.Bt = (NT + 255) / 256; fa.Bd = (ND + 255) / 256;

    finalize_k<<<fa.Bt + fa.Bd + 1, 256, 0, stream>>>(fa);
}